// Round 4
// baseline (1557.451 us; speedup 1.0000x reference)
//
#include <hip/hip_runtime.h>
#include <math.h>

typedef unsigned short u16;
typedef unsigned int u32;

constexpr int kB = 16, kL = 512, kS = 1024, kD = 512, kM = 64;

typedef __attribute__((ext_vector_type(8))) short u16x8;
typedef __attribute__((ext_vector_type(8))) _Float16 f16x8;
typedef __attribute__((ext_vector_type(4))) float f32x4;

__device__ __forceinline__ u16 f2h(float f) {
    _Float16 h = (_Float16)f;
    return *(u16*)&h;
}
__device__ __forceinline__ float h2f(u16 u) {
    _Float16 h = *(_Float16*)&u;
    return (float)h;
}

// ---------------------------------------------------------------------------
// fp16 MFMA GEMM: C[r,n] = op( sum_k A[r,k]*W[n,k] + bias + resid )
// A: R x K fp16 row-major; W: N x K fp16 row-major (X @ W.T).
// 128x128 tile, BK=64, 256 thr (4 waves 2x2), wave = 64x64 via 4x4 16x16x32.
// flags: 1=relu, 4=conv-mode (K=4608; A = base of 3 fp16 T buffers stride
//        kB*kL*kD; W = PK[t][j][n][d] fp16), 8=write fp16 Ch, 16=write f32 Cout
// ---------------------------------------------------------------------------
__global__ __launch_bounds__(256, 4) void gemm_fp16(
    const u16* __restrict__ Abase, const u16* __restrict__ Wbase,
    const float* __restrict__ bias, const float* __restrict__ resid,
    float* __restrict__ Cout, u16* __restrict__ Ch,
    int R, int N, int K, int flags)
{
    __shared__ __attribute__((aligned(16))) u16 Abuf[128 * 64];
    __shared__ __attribute__((aligned(16))) u16 Bbuf[128 * 64];
    const int tid = threadIdx.x;
    const int lane = tid & 63;
    const int wave = tid >> 6;
    const int wr = wave >> 1, wc = wave & 1;
    const int ln15 = lane & 15, lq = lane >> 4;
    const int r0 = blockIdx.y * 128, n0 = blockIdx.x * 128;

    f32x4 acc[4][4];
#pragma unroll
    for (int m = 0; m < 4; ++m)
#pragma unroll
        for (int n = 0; n < 4; ++n) acc[m][n] = (f32x4){0.f, 0.f, 0.f, 0.f};

    for (int k0 = 0; k0 < K; k0 += 64) {
        // conv-mode decode (uniform per iteration)
        int t = 0, jsh = 0, dk = k0;
        if (flags & 4) {
            t = k0 / 1536;
            int rem = k0 - t * 1536;
            jsh = rem >> 9;
            dk = rem & 511;
        }
        u16x8 av[4], bv[4];
#pragma unroll
        for (int it = 0; it < 4; ++it) {
            int c = it * 256 + tid;
            int row = c >> 3, j = c & 7;
            int jj = j ^ (row & 7);
            size_t aoff, boff;
            int grow = r0 + row;
            int gcol = n0 + row;
            if (flags & 4) {
                int b_ = grow >> 9, l_ = grow & 511;
                int sr = (b_ << 9) | ((l_ + jsh + 511) & 511);
                aoff = (size_t)t * (size_t)(kB * kL * kD) + (size_t)sr * 512 + dk + jj * 8;
                boff = (((size_t)(t * 3 + jsh) * 512) + gcol) * 512 + dk + jj * 8;
            } else {
                aoff = (size_t)grow * K + k0 + jj * 8;
                boff = (size_t)gcol * K + k0 + jj * 8;
            }
            av[it] = *(const u16x8*)(Abase + aoff);
            bv[it] = *(const u16x8*)(Wbase + boff);
        }
        __syncthreads();
#pragma unroll
        for (int it = 0; it < 4; ++it) {
            int c = it * 256 + tid;
            int row = c >> 3, j = c & 7;
            *(u16x8*)&Abuf[row * 64 + j * 8] = av[it];
            *(u16x8*)&Bbuf[row * 64 + j * 8] = bv[it];
        }
        __syncthreads();
#pragma unroll
        for (int h = 0; h < 2; ++h) {
            int kg = lq + h * 4;
            f16x8 af[4], bfv[4];
#pragma unroll
            for (int m = 0; m < 4; ++m) {
                int row = wr * 64 + m * 16 + ln15;
                af[m] = *(const f16x8*)&Abuf[row * 64 + ((kg ^ (row & 7)) << 3)];
            }
#pragma unroll
            for (int n = 0; n < 4; ++n) {
                int col = wc * 64 + n * 16 + ln15;
                bfv[n] = *(const f16x8*)&Bbuf[col * 64 + ((kg ^ (col & 7)) << 3)];
            }
#pragma unroll
            for (int m = 0; m < 4; ++m)
#pragma unroll
                for (int n = 0; n < 4; ++n)
                    acc[m][n] = __builtin_amdgcn_mfma_f32_16x16x32_f16(af[m], bfv[n], acc[m][n], 0, 0, 0);
        }
        __syncthreads();
    }

#pragma unroll
    for (int m = 0; m < 4; ++m) {
#pragma unroll
        for (int n = 0; n < 4; ++n) {
            int gc = n0 + wc * 64 + n * 16 + ln15;
            float bv_ = bias ? bias[gc] : 0.f;
#pragma unroll
            for (int rg = 0; rg < 4; ++rg) {
                int gr = r0 + wr * 64 + m * 16 + lq * 4 + rg;
                float val = acc[m][n][rg] + bv_;
                if (resid) val += resid[(size_t)gr * N + gc];
                if (flags & 1) val = fmaxf(val, 0.f);
                if (flags & 16) Cout[(size_t)gr * N + gc] = val;
                if (flags & 8)  Ch[(size_t)gr * N + gc] = f2h(val);
            }
        }
    }
}

// ---------------------------------------------------------------------------
// Twiddle tables: tw[(mg*N + l)*8 + mm*2 + {0:cos,1:-sin}], modes m = mg*4+mm
// ---------------------------------------------------------------------------
__global__ void twiddle_gen(float* __restrict__ tw, int N)
{
    int idx = blockIdx.x * 256 + threadIdx.x;
    if (idx >= 16 * N * 4) return;
    int mg = idx / (N * 4);
    int rem = idx - mg * N * 4;
    int l = rem >> 2, mm = rem & 3;
    int m = mg * 4 + mm;
    int ph = (int)(((long long)m * (long long)l) % N);
    float ang = 6.283185307179586f * (float)ph / (float)N;
    float s_, c_;
    sincosf(ang, &s_, &c_);
    tw[((size_t)mg * N + l) * 8 + mm * 2 + 0] = c_;
    tw[((size_t)mg * N + l) * 8 + mm * 2 + 1] = -s_;
}

// ---------------------------------------------------------------------------
// Forward DFT, first 64 modes, table-driven. in_half: input fp16 else fp32.
// Output normal (B,64,D) or transposed [d][b][m].
// ---------------------------------------------------------------------------
__global__ __launch_bounds__(512) void dft_fwd2(
    const void* __restrict__ Ain, int in_half, const float* __restrict__ tw,
    float* __restrict__ Fr, float* __restrict__ Fi, int N, int transposed)
{
    __shared__ float twl[8192];
    const int blk = blockIdx.x;
    const int b = blk >> 4, mg = blk & 15;
    const int m0 = mg * 4;
    const int tid = threadIdx.x;
    for (int idx = tid; idx < N * 8; idx += 512)
        twl[idx] = tw[(size_t)mg * N * 8 + idx];
    __syncthreads();

    const int d = tid;
    float fr0 = 0, fi0 = 0, fr1 = 0, fi1 = 0, fr2 = 0, fi2 = 0, fr3 = 0, fi3 = 0;
    const float* A32 = (const float*)Ain + (size_t)b * N * kD + d;
    const u16*   A16 = (const u16*)Ain + (size_t)b * N * kD + d;
    for (int l = 0; l < N; ++l) {
        float a = in_half ? h2f(A16[(size_t)l * kD]) : A32[(size_t)l * kD];
        float4 t0 = *(const float4*)&twl[l * 8];
        float4 t1 = *(const float4*)&twl[l * 8 + 4];
        fr0 += a * t0.x; fi0 += a * t0.y;
        fr1 += a * t0.z; fi1 += a * t0.w;
        fr2 += a * t1.x; fi2 += a * t1.y;
        fr3 += a * t1.z; fi3 += a * t1.w;
    }
    if (transposed) {
        size_t base = ((size_t)d * kB + b) * kM + m0;
        Fr[base + 0] = fr0; Fr[base + 1] = fr1; Fr[base + 2] = fr2; Fr[base + 3] = fr3;
        Fi[base + 0] = fi0; Fi[base + 1] = fi1; Fi[base + 2] = fi2; Fi[base + 3] = fi3;
    } else {
        size_t base = ((size_t)b * kM + m0) * kD + d;
        Fr[base] = fr0; Fr[base + 512] = fr1; Fr[base + 1024] = fr2; Fr[base + 1536] = fr3;
        Fi[base] = fi0; Fi[base + 512] = fi1; Fi[base + 1024] = fi2; Fi[base + 1536] = fi3;
    }
}

// ---------------------------------------------------------------------------
// FEB per-mode contraction, d-chunked partials.
// ---------------------------------------------------------------------------
__global__ __launch_bounds__(256) void feb_part(
    const float* __restrict__ qtr, const float* __restrict__ qti,
    const float* __restrict__ wr, const float* __restrict__ wi,
    float* __restrict__ part)
{
    __shared__ float sqr[4][16][64], sqi[4][16][64];
    const int eb = blockIdx.x;
    const int ch = blockIdx.y;
    const int tid = threadIdx.x;
    const int mm = tid & 63, ee = tid >> 6;
    const int e = eb * 4 + ee;
    float ar[16], ai[16];
#pragma unroll
    for (int b_ = 0; b_ < 16; ++b_) { ar[b_] = 0.f; ai[b_] = 0.f; }

    const int dbeg = ch * 128, dend = dbeg + 128;
    for (int d0 = dbeg; d0 < dend; d0 += 4) {
        __syncthreads();
#pragma unroll
        for (int rep = 0; rep < 16; ++rep) {
            int idx = tid + rep * 256;
            int m_ = idx & 63, b_ = (idx >> 6) & 15, dd_ = idx >> 10;
            size_t g = ((size_t)(d0 + dd_) * kB + b_) * kM + m_;
            sqr[dd_][b_][m_] = qtr[g];
            sqi[dd_][b_][m_] = qti[g];
        }
        __syncthreads();
#pragma unroll
        for (int dd = 0; dd < 4; ++dd) {
            size_t wofs = ((size_t)(d0 + dd) * kD + e) * kM + mm;
            float wrv = wr[wofs], wiv = wi[wofs];
#pragma unroll
            for (int b_ = 0; b_ < 16; ++b_) {
                float qr = sqr[dd][b_][mm], qi = sqi[dd][b_][mm];
                ar[b_] += qr * wrv - qi * wiv;
                ai[b_] += qr * wiv + qi * wrv;
            }
        }
    }
    float* reg = part + (size_t)(ch * 128 + eb) * 8192;
#pragma unroll
    for (int b_ = 0; b_ < 16; ++b_) {
        reg[(b_ * 64 + mm) * 4 + ee] = ar[b_];
        reg[4096 + (b_ * 64 + mm) * 4 + ee] = ai[b_];
    }
}

__global__ __launch_bounds__(256) void feb_reduce(
    const float* __restrict__ part, float* __restrict__ omr, float* __restrict__ omi)
{
    int idx = blockIdx.x * 256 + threadIdx.x;   // 0..524287
    int e = idx & 511, bm = idx >> 9;
    int eb = e >> 2, ee = e & 3;
    float r = 0.f, im = 0.f;
#pragma unroll
    for (int ch = 0; ch < 4; ++ch) {
        const float* reg = part + (size_t)(ch * 128 + eb) * 8192 + (bm * 4 + ee);
        r += reg[0];
        im += reg[4096];
    }
    omr[idx] = r;
    omi[idx] = im;
}

// ---------------------------------------------------------------------------
// Inverse real DFT (modes 0..63 -> length 512), numpy irfft semantics.
// Optional fp32 residual; writes f32 out and/or fp16 out_h.
// ---------------------------------------------------------------------------
__global__ __launch_bounds__(512) void irdft(
    const float* __restrict__ omr, const float* __restrict__ omi,
    const float* __restrict__ resid, float* __restrict__ out, u16* __restrict__ out_h)
{
    __shared__ float tc[64][16], tsn[64][16];
    const int blk = blockIdx.x;
    const int b = blk >> 5;
    const int l0 = (blk & 31) << 4;
    const int tid = threadIdx.x;

    for (int idx = tid; idx < 1024; idx += 512) {
        int m_ = idx >> 4, ll = idx & 15;
        int ph = (m_ * (l0 + ll)) & 511;
        float ang = 6.283185307179586f * (float)ph / 512.0f;
        float s_, c_;
        sincosf(ang, &s_, &c_);
        tc[m_][ll] = c_; tsn[m_][ll] = s_;
    }
    __syncthreads();

    const int e = tid;
    float acc[16];
    float r0 = omr[((size_t)b * kM) * kD + e];
#pragma unroll
    for (int ll = 0; ll < 16; ++ll) acc[ll] = r0;
    for (int m_ = 1; m_ < 64; ++m_) {
        float r = 2.f * omr[((size_t)b * kM + m_) * kD + e];
        float i_ = 2.f * omi[((size_t)b * kM + m_) * kD + e];
#pragma unroll
        for (int ll = 0; ll < 16; ++ll) acc[ll] += r * tc[m_][ll] - i_ * tsn[m_][ll];
    }
    const float inv = 1.0f / 512.0f;
#pragma unroll
    for (int ll = 0; ll < 16; ++ll) {
        size_t o = ((size_t)b * kL + l0 + ll) * kD + e;
        float v = acc[ll] * inv;
        if (resid) v += resid[o];
        if (out) out[o] = v;
        if (out_h) out_h[o] = f2h(v);
    }
}

// ---------------------------------------------------------------------------
// Spectral cross attention, one block per (b,h). fp32.
// ---------------------------------------------------------------------------
__global__ __launch_bounds__(256) void spectral_attn(
    const float* __restrict__ qfr, const float* __restrict__ qfi,
    const float* __restrict__ kfr, const float* __restrict__ kfi,
    const float* __restrict__ vfr, const float* __restrict__ vfi,
    float* __restrict__ omr, float* __restrict__ omi)
{
    __shared__ float kr[64][65], ki[64][65], sat[64][65];
    const int b = blockIdx.x >> 3, h = blockIdx.x & 7;
    const int tid = threadIdx.x;
    const int dbase = h * 64;

    for (int idx = tid; idx < 4096; idx += 256) {
        int j = idx >> 6, dd = idx & 63;
        kr[j][dd] = kfr[((size_t)b * kM + j) * kD + dbase + dd];
        ki[j][dd] = kfi[((size_t)b * kM + j) * kD + dbase + dd];
    }
    __syncthreads();

    const int i_ = tid >> 2, jg = tid & 3;
    float s[16];
#pragma unroll
    for (int jj = 0; jj < 16; ++jj) s[jj] = 0.f;
    const float* qrp = qfr + ((size_t)b * kM + i_) * kD + dbase;
    const float* qip = qfi + ((size_t)b * kM + i_) * kD + dbase;
    for (int dd = 0; dd < 64; ++dd) {
        float qr = qrp[dd], qi = qip[dd];
#pragma unroll
        for (int jj = 0; jj < 16; ++jj) {
            int j = jg * 16 + jj;
            s[jj] += qr * kr[j][dd] + qi * ki[j][dd];
        }
    }
    float mx = s[0];
#pragma unroll
    for (int jj = 1; jj < 16; ++jj) mx = fmaxf(mx, s[jj]);
    mx = fmaxf(mx, __shfl_xor(mx, 1));
    mx = fmaxf(mx, __shfl_xor(mx, 2));
    float sum = 0.f;
#pragma unroll
    for (int jj = 0; jj < 16; ++jj) { s[jj] = expf(s[jj] - mx); sum += s[jj]; }
    sum += __shfl_xor(sum, 1);
    sum += __shfl_xor(sum, 2);
    float rinv = 1.0f / sum;
#pragma unroll
    for (int jj = 0; jj < 16; ++jj) sat[i_][jg * 16 + jj] = s[jj] * rinv;
    __syncthreads();

    const int dd = tid & 63, ig = tid >> 6;
    float ar[16], ai[16];
#pragma unroll
    for (int ii = 0; ii < 16; ++ii) { ar[ii] = 0.f; ai[ii] = 0.f; }
    for (int j = 0; j < 64; ++j) {
        float vr = vfr[((size_t)b * kM + j) * kD + dbase + dd];
        float vi = vfi[((size_t)b * kM + j) * kD + dbase + dd];
#pragma unroll
        for (int ii = 0; ii < 16; ++ii) {
            float a = sat[ig * 16 + ii][j];
            ar[ii] += a * vr;
            ai[ii] += a * vi;
        }
    }
#pragma unroll
    for (int ii = 0; ii < 16; ++ii) {
        size_t o = ((size_t)b * kM + ig * 16 + ii) * kD + dbase + dd;
        omr[o] = ar[ii];
        omi[o] = ai[ii];
    }
}

// ---------------------------------------------------------------------------
// MoE decomposition epilogue: gate softmax + 3 avgpools + mix + subtract.
// Writes optional f32 xout, optional fp16 xout_h, fp16 trend tout_h.
// ---------------------------------------------------------------------------
__global__ __launch_bounds__(256) void decomp_apply(
    const float* __restrict__ x, const float* __restrict__ logits,
    float* __restrict__ xout, u16* __restrict__ xout_h, u16* __restrict__ tout_h)
{
    int idx = blockIdx.x * 256 + threadIdx.x;
    if (idx >= kB * kL * kD) return;
    int d = idx & 511;
    int l = (idx >> 9) & 511;
    int b = idx >> 18;
    const float* lg = logits + ((size_t)b * kL + l) * 3;
    float g0 = lg[0], g1 = lg[1], g2 = lg[2];
    float m = fmaxf(g0, fmaxf(g1, g2));
    float e0 = expf(g0 - m), e1 = expf(g1 - m), e2 = expf(g2 - m);
    float inv = 1.0f / (e0 + e1 + e2);
    g0 = e0 * inv; g1 = e1 * inv; g2 = e2 * inv;

    const float* xb = x + (size_t)b * kL * kD + d;
    float v[7];
#pragma unroll
    for (int j = 0; j < 7; ++j) {
        int ls = l + j - 3;
        v[j] = (ls >= 0 && ls < kL) ? xb[(size_t)ls * kD] : 0.f;
    }
    float s3 = (v[2] + v[3] + v[4]) * (1.0f / 3.0f);
    float s5 = (v[1] + v[2] + v[3] + v[4] + v[5]) * 0.2f;
    float s7 = (v[0] + v[1] + v[2] + v[3] + v[4] + v[5] + v[6]) * (1.0f / 7.0f);
    float trend = g0 * s3 + g1 * s5 + g2 * s7;
    float res = v[3] - trend;
    if (xout) xout[idx] = res;
    if (xout_h) xout_h[idx] = f2h(res);
    tout_h[idx] = f2h(trend);
}

// ---------------------------------------------------------------------------
// Gate layer 2: logits[r][n] = b2[n] + sum_c GH[r,c]*w2[n,c]  (N=3, K=256)
// ---------------------------------------------------------------------------
__global__ __launch_bounds__(256) void gate2(
    const u16* __restrict__ GH, const float* __restrict__ w2,
    const float* __restrict__ b2, float* __restrict__ logits)
{
    __shared__ float w2l[3][256];
    int tid = threadIdx.x;
    for (int i = tid; i < 768; i += 256) w2l[i >> 8][i & 255] = w2[i];
    __syncthreads();
    int r = blockIdx.x * 256 + tid;
    float s0 = b2[0], s1 = b2[1], s2 = b2[2];
    const u16* g = GH + (size_t)r * 256;
    for (int c0 = 0; c0 < 256; c0 += 8) {
        uint4 u = *(const uint4*)&g[c0];
        u32 w[4] = {u.x, u.y, u.z, u.w};
#pragma unroll
        for (int p = 0; p < 4; ++p) {
            float f0 = h2f((u16)(w[p] & 0xFFFF));
            float f1 = h2f((u16)(w[p] >> 16));
            int c = c0 + p * 2;
            s0 += f0 * w2l[0][c] + f1 * w2l[0][c + 1];
            s1 += f0 * w2l[1][c] + f1 * w2l[1][c + 1];
            s2 += f0 * w2l[2][c] + f1 * w2l[2][c + 1];
        }
    }
    logits[(size_t)r * 3 + 0] = s0;
    logits[(size_t)r * 3 + 1] = s1;
    logits[(size_t)r * 3 + 2] = s2;
}

// ---------------------------------------------------------------------------
__global__ void cast_f32_f16(const float* __restrict__ src, u16* __restrict__ dst, int n)
{
    int idx = (blockIdx.x * 256 + threadIdx.x) * 4;
    if (idx >= n) return;
    float4 v = *(const float4*)&src[idx];
    ushort4 o;
    o.x = f2h(v.x); o.y = f2h(v.y); o.z = f2h(v.z); o.w = f2h(v.w);
    *(ushort4*)&dst[idx] = o;
}

// Repack conv weights p[o,d,j] (fp32) -> pk[t][j][o][d] (fp16)
__global__ void repack_p(const float* __restrict__ p1, const float* __restrict__ p2,
                         const float* __restrict__ p3, u16* __restrict__ pk)
{
    int idx = blockIdx.x * 256 + threadIdx.x;
    if (idx >= 3 * 3 * 512 * 512) return;
    int d = idx & 511;
    int oc = (idx >> 9) & 511;
    int j = (idx / (512 * 512)) % 3;
    int t = idx / (3 * 512 * 512);
    const float* p = (t == 0) ? p1 : (t == 1) ? p2 : p3;
    pk[idx] = f2h(p[(size_t)oc * 512 * 3 + (size_t)d * 3 + j]);
}

// ---------------------------------------------------------------------------
extern "C" void kernel_launch(void* const* d_in, const int* in_sizes, int n_in,
                              void* d_out, int out_size, void* d_ws, size_t ws_size,
                              hipStream_t stream)
{
    const float* x_in   = (const float*)d_in[0];
    const float* cross  = (const float*)d_in[1];
    const float* feb_wr = (const float*)d_in[2];
    const float* feb_wi = (const float*)d_in[3];
    const float* wq = (const float*)d_in[4];
    const float* bq = (const float*)d_in[5];
    const float* wk = (const float*)d_in[6];
    const float* bk = (const float*)d_in[7];
    const float* wv = (const float*)d_in[8];
    const float* bv = (const float*)d_in[9];
    const float* wo = (const float*)d_in[10];
    const float* bo = (const float*)d_in[11];
    const float* w_ff1 = (const float*)d_in[12];
    const float* w_ff2 = (const float*)d_in[13];
    const float* d1_w1 = (const float*)d_in[14];
    const float* d1_b1 = (const float*)d_in[15];
    const float* d1_w2 = (const float*)d_in[16];
    const float* d1_b2 = (const float*)d_in[17];
    const float* d2_w1 = (const float*)d_in[18];
    const float* d2_b1 = (const float*)d_in[19];
    const float* d2_w2 = (const float*)d_in[20];
    const float* d2_b2 = (const float*)d_in[21];
    const float* d3_w1 = (const float*)d_in[22];
    const float* d3_b1 = (const float*)d_in[23];
    const float* d3_w2 = (const float*)d_in[24];
    const float* d3_b2 = (const float*)d_in[25];
    const float* p1 = (const float*)d_in[26];
    const float* p2 = (const float*)d_in[27];
    const float* p3 = (const float*)d_in[28];

    // workspace layout (float offsets), peak ~41.97M floats = 167.9 MB
    float* ws = (float*)d_ws;
    float* X    = ws;                      // 4,194,304
    float* XT   = ws + 4194304;            // 4,194,304
    u16*  Kh    = (u16*)(ws + 8388608);    // 8,388,608 u16 (FEBP overlay A; HIDh E)
    u16*  Vh    = (u16*)(ws + 12582912);   // 8,388,608 u16
    u16*  Q0h   = (u16*)(ws + 16777216);   // 4,194,304 u16 (Qh overlay post-attn)
    u16*  T1h   = (u16*)(ws + 18874368);   // 4,194,304 u16 each; T1,T2,T3 contiguous
    u16*  T2h   = (u16*)(ws + 20971520);
    u16*  T3h   = (u16*)(ws + 23068672);
    float* QFR  = ws + 25165824;           // 8 x 524,288
    float* QFI  = QFR + 524288;
    float* KFR  = QFI + 524288;
    float* KFI  = KFR + 524288;
    float* VFR  = KFI + 524288;
    float* VFI  = VFR + 524288;
    float* OMR  = VFI + 524288;
    float* OMI  = OMR + 524288;
    u16*  crossh = (u16*)(ws + 29360128);  // 8,388,608 u16
    u16*  Xh    = (u16*)(ws + 33554432);   // 4,194,304 u16
    u16*  XTh   = (u16*)(ws + 35651584);   // 4,194,304 u16
    u16*  GHh   = (u16*)(ws + 37748736);   // 2,097,152 u16
    float* GLG  = ws + 38797312;           // 24,576
    u16*  wqh   = (u16*)(ws + 38821888);   // 262,144 u16 each
    u16*  wkh   = wqh + 262144;
    u16*  wvh   = wkh + 262144;
    u16*  woh   = wvh + 262144;
    u16*  ff1h  = woh + 262144;            // 1,048,576 u16
    u16*  ff2h  = ff1h + 1048576;          // 1,048,576 u16
    u16*  d1w1h = ff2h + 1048576;          // 131,072 u16 each
    u16*  d2w1h = d1w1h + 131072;
    u16*  d3w1h = d2w1h + 131072;
    u16*  PKh   = d3w1h + 131072;          // 2,359,296 u16
    float* TW512  = ws + 41771008;         // 65,536
    float* TW1024 = ws + 41836544;         // 131,072 -> end 41,967,616
    float* FEBP = (float*)Kh;              // phase A overlay (4,194,304 f32)
    u16*  HIDh  = Kh;                      // phase E overlay (16,777,216 u16)
    u16*  Qh    = Q0h;                     // phase C post-attn overlay

    float* outx = (float*)d_out;
    float* outt = outx + 4194304;

    auto gemm = [&](const u16* A, const u16* W, const float* bias, const float* resid,
                    float* C, u16* Cb, int R, int N, int K, int flags) {
        dim3 g(N / 128, R / 128);
        hipLaunchKernelGGL(gemm_fp16, g, dim3(256), 0, stream, A, W, bias, resid, C, Cb, R, N, K, flags);
    };
    auto cast = [&](const float* s, u16* d, int n) {
        hipLaunchKernelGGL(cast_f32_f16, dim3(n / 1024), dim3(256), 0, stream, s, d, n);
    };

    // ---- Prep: fp16 weight/operand casts, twiddles, conv repack ----
    cast(wq, wqh, 262144);
    cast(wk, wkh, 262144);
    cast(wv, wvh, 262144);
    cast(wo, woh, 262144);
    cast(w_ff1, ff1h, 1048576);
    cast(w_ff2, ff2h, 1048576);
    cast(d1_w1, d1w1h, 131072);
    cast(d2_w1, d2w1h, 131072);
    cast(d3_w1, d3w1h, 131072);
    cast(cross, crossh, 8388608);
    hipLaunchKernelGGL(twiddle_gen, dim3(128), dim3(256), 0, stream, TW512, 512);
    hipLaunchKernelGGL(twiddle_gen, dim3(256), dim3(256), 0, stream, TW1024, 1024);
    hipLaunchKernelGGL(repack_p, dim3(9216), dim3(256), 0, stream, p1, p2, p3, PKh);

    // ---- Phase A: x = x + fourier_block(x) ----
    hipLaunchKernelGGL(dft_fwd2, dim3(256), dim3(512), 0, stream,
                       (const void*)x_in, 0, TW512, QFR, QFI, 512, 1);
    hipLaunchKernelGGL(feb_part, dim3(128, 4), dim3(256), 0, stream, QFR, QFI, feb_wr, feb_wi, FEBP);
    hipLaunchKernelGGL(feb_reduce, dim3(2048), dim3(256), 0, stream, FEBP, OMR, OMI);
    hipLaunchKernelGGL(irdft, dim3(512), dim3(512), 0, stream, OMR, OMI, x_in, X, Xh);

    // ---- Phase B: decomp1 ----
    gemm(Xh, d1w1h, d1_b1, nullptr, nullptr, GHh, 8192, 256, 512, 1 | 8);
    hipLaunchKernelGGL(gate2, dim3(32), dim3(256), 0, stream, GHh, d1_w2, d1_b2, GLG);
    hipLaunchKernelGGL(decomp_apply, dim3(16384), dim3(256), 0, stream, X, GLG, XT, XTh, T1h);

    // ---- Phase C: x = x + fourier_cross(x, cross) ----
    gemm(XTh, wqh, bq, nullptr, nullptr, Q0h, 8192, 512, 512, 8);
    gemm(crossh, wkh, bk, nullptr, nullptr, Kh, 16384, 512, 512, 8);
    gemm(crossh, wvh, bv, nullptr, nullptr, Vh, 16384, 512, 512, 8);
    hipLaunchKernelGGL(dft_fwd2, dim3(256), dim3(512), 0, stream,
                       (const void*)Q0h, 1, TW512, QFR, QFI, 512, 0);
    hipLaunchKernelGGL(dft_fwd2, dim3(256), dim3(512), 0, stream,
                       (const void*)Kh, 1, TW1024, KFR, KFI, 1024, 0);
    hipLaunchKernelGGL(dft_fwd2, dim3(256), dim3(512), 0, stream,
                       (const void*)Vh, 1, TW1024, VFR, VFI, 1024, 0);
    hipLaunchKernelGGL(spectral_attn, dim3(128), dim3(256), 0, stream,
                       QFR, QFI, KFR, KFI, VFR, VFI, OMR, OMI);
    hipLaunchKernelGGL(irdft, dim3(512), dim3(512), 0, stream,
                       OMR, OMI, (const float*)nullptr, (float*)nullptr, Qh);
    gemm(Qh, woh, bo, XT, X, Xh, 8192, 512, 512, 16 | 8);

    // ---- Phase D: decomp2 ----
    gemm(Xh, d2w1h, d2_b1, nullptr, nullptr, GHh, 8192, 256, 512, 1 | 8);
    hipLaunchKernelGGL(gate2, dim3(32), dim3(256), 0, stream, GHh, d2_w2, d2_b2, GLG);
    hipLaunchKernelGGL(decomp_apply, dim3(16384), dim3(256), 0, stream, X, GLG, XT, XTh, T2h);

    // ---- Phase E: FFN ----
    gemm(XTh, ff1h, nullptr, nullptr, nullptr, HIDh, 8192, 2048, 512, 1 | 8);
    gemm(HIDh, ff2h, nullptr, XT, X, Xh, 8192, 512, 2048, 16 | 8);

    // ---- Phase F: decomp3 -> d_out x ----
    gemm(Xh, d3w1h, d3_b1, nullptr, nullptr, GHh, 8192, 256, 512, 1 | 8);
    hipLaunchKernelGGL(gate2, dim3(32), dim3(256), 0, stream, GHh, d3_w2, d3_b2, GLG);
    hipLaunchKernelGGL(decomp_apply, dim3(16384), dim3(256), 0, stream, X, GLG, outx,
                       (u16*)nullptr, T3h);

    // ---- Phase G: residual_trend, one K=4608 fp16 GEMM over (t,j) ----
    gemm(T1h, PKh, nullptr, nullptr, outt, nullptr, 8192, 512, 4608, 4 | 16);

    (void)in_sizes; (void)n_in; (void)out_size; (void)ws_size;
}

// Round 5
// 770.113 us; speedup vs baseline: 2.0224x; 2.0224x over previous
//
#include <hip/hip_runtime.h>
#include <math.h>

typedef unsigned short u16;
typedef unsigned int u32;
typedef unsigned long long u64;

constexpr int kB = 16, kL = 512, kS = 1024, kD = 512, kM = 64;

typedef __attribute__((ext_vector_type(8))) short u16x8;
typedef __attribute__((ext_vector_type(8))) _Float16 f16x8;
typedef __attribute__((ext_vector_type(4))) float f32x4;

__device__ __forceinline__ u16 f2h(float f) {
    _Float16 h = (_Float16)f;
    return *(u16*)&h;
}
__device__ __forceinline__ float h2f(u16 u) {
    _Float16 h = *(_Float16*)&u;
    return (float)h;
}

// ---------------------------------------------------------------------------
// fp16 MFMA GEMM, z-batched: C[z][r,n] = op( sum_k A[r,k]*W[z][n,k] + ... )
// A: R x K fp16 row-major (shared across z); W: N x K fp16 rows (X @ W.T).
// 128x128 tile, BK=64, 256 thr (4 waves 2x2), wave = 64x64 via 4x4 16x16x32.
// flags: 1=relu, 4=conv-mode (z=1; K=4608; A = 3 fp16 T buffers stride B*L*D;
//        W = PK[t][j][n][d]), 8=write fp16 Ch[r][n], 16=write f32 Cout[r][n],
//        32=write fp16 transposed Ch[b][n][l] where b=r>>lrsh, l=r&((1<<lrsh)-1)
// ---------------------------------------------------------------------------
__global__ __launch_bounds__(256, 4) void gemm_fp16(
    const u16* __restrict__ Abase, const u16* __restrict__ Wbase,
    const float* __restrict__ bias, const float* __restrict__ resid,
    float* __restrict__ Cout, u16* __restrict__ Ch,
    int R, int N, int K, int flags,
    u64 zsW, u64 zsC, u64 zsR, int lrsh)
{
    __shared__ __attribute__((aligned(16))) u16 Abuf[128 * 64];
    __shared__ __attribute__((aligned(16))) u16 Bbuf[128 * 64];
    const int zz = blockIdx.z;
    Wbase += (u64)zz * zsW;
    if (Cout) Cout += (u64)zz * zsC;
    if (Ch)   Ch   += (u64)zz * zsC;
    if (resid) resid += (u64)zz * zsR;

    const int tid = threadIdx.x;
    const int lane = tid & 63;
    const int wave = tid >> 6;
    const int wr = wave >> 1, wc = wave & 1;
    const int ln15 = lane & 15, lq = lane >> 4;
    const int r0 = blockIdx.y * 128, n0 = blockIdx.x * 128;

    f32x4 acc[4][4];
#pragma unroll
    for (int m = 0; m < 4; ++m)
#pragma unroll
        for (int n = 0; n < 4; ++n) acc[m][n] = (f32x4){0.f, 0.f, 0.f, 0.f};

    for (int k0 = 0; k0 < K; k0 += 64) {
        // conv-mode decode (uniform per iteration)
        int t = 0, jsh = 0, dk = k0;
        if (flags & 4) {
            t = k0 / 1536;
            int rem = k0 - t * 1536;
            jsh = rem >> 9;
            dk = rem & 511;
        }
        u16x8 av[4], bv[4];
#pragma unroll
        for (int it = 0; it < 4; ++it) {
            int c = it * 256 + tid;
            int row = c >> 3, j = c & 7;
            int jj = j ^ (row & 7);
            size_t aoff, boff;
            int grow = r0 + row;
            int gcol = n0 + row;
            if (flags & 4) {
                int b_ = grow >> 9, l_ = grow & 511;
                int sr = (b_ << 9) | ((l_ + jsh + 511) & 511);
                aoff = (size_t)t * (size_t)(kB * kL * kD) + (size_t)sr * 512 + dk + jj * 8;
                boff = (((size_t)(t * 3 + jsh) * 512) + gcol) * 512 + dk + jj * 8;
            } else {
                aoff = (size_t)grow * K + k0 + jj * 8;
                boff = (size_t)gcol * K + k0 + jj * 8;
            }
            av[it] = *(const u16x8*)(Abase + aoff);
            bv[it] = *(const u16x8*)(Wbase + boff);
        }
        __syncthreads();
#pragma unroll
        for (int it = 0; it < 4; ++it) {
            int c = it * 256 + tid;
            int row = c >> 3, j = c & 7;
            *(u16x8*)&Abuf[row * 64 + j * 8] = av[it];
            *(u16x8*)&Bbuf[row * 64 + j * 8] = bv[it];
        }
        __syncthreads();
#pragma unroll
        for (int h = 0; h < 2; ++h) {
            int kg = lq + h * 4;
            f16x8 af[4], bfv[4];
#pragma unroll
            for (int m = 0; m < 4; ++m) {
                int row = wr * 64 + m * 16 + ln15;
                af[m] = *(const f16x8*)&Abuf[row * 64 + ((kg ^ (row & 7)) << 3)];
            }
#pragma unroll
            for (int n = 0; n < 4; ++n) {
                int col = wc * 64 + n * 16 + ln15;
                bfv[n] = *(const f16x8*)&Bbuf[col * 64 + ((kg ^ (col & 7)) << 3)];
            }
#pragma unroll
            for (int m = 0; m < 4; ++m)
#pragma unroll
                for (int n = 0; n < 4; ++n)
                    acc[m][n] = __builtin_amdgcn_mfma_f32_16x16x32_f16(af[m], bfv[n], acc[m][n], 0, 0, 0);
        }
        __syncthreads();
    }

#pragma unroll
    for (int m = 0; m < 4; ++m) {
#pragma unroll
        for (int n = 0; n < 4; ++n) {
            int gc = n0 + wc * 64 + n * 16 + ln15;
            float bv_ = bias ? bias[gc] : 0.f;
            int gr0 = r0 + wr * 64 + m * 16 + lq * 4;
            float v[4];
#pragma unroll
            for (int rg = 0; rg < 4; ++rg) {
                int gr = gr0 + rg;
                float val = acc[m][n][rg] + bv_;
                if (resid) val += resid[(size_t)gr * N + gc];
                if (flags & 1) val = fmaxf(val, 0.f);
                if (flags & 16) Cout[(size_t)gr * N + gc] = val;
                if (flags & 8)  Ch[(size_t)gr * N + gc] = f2h(val);
                v[rg] = val;
            }
            if (flags & 32) {
                int bb = gr0 >> lrsh;
                int l_ = gr0 & ((1 << lrsh) - 1);
                ushort4 o;
                o.x = f2h(v[0]); o.y = f2h(v[1]); o.z = f2h(v[2]); o.w = f2h(v[3]);
                *(ushort4*)&Ch[(((size_t)bb * N + gc) << lrsh) + l_] = o;
            }
        }
    }
}

// ---------------------------------------------------------------------------
// Forward DFT twiddle matrix TW[r][l], r in [0,128): r<64 -> cos(2*pi*r*l/N),
// r>=64 -> -sin(2*pi*(r-64)*l/N). fp16.
// ---------------------------------------------------------------------------
__global__ void dft_tw_gen(u16* __restrict__ twh, int N)
{
    int idx = blockIdx.x * 256 + threadIdx.x;
    if (idx >= 128 * N) return;
    int r = idx / N, l = idx - r * N;
    int m = r & 63;
    int ph = (int)(((long long)m * l) % N);
    float ang = 6.283185307179586f * (float)ph / (float)N;
    float s_, c_;
    sincosf(ang, &s_, &c_);
    twh[idx] = f2h((r < 64) ? c_ : -s_);
}

// ---------------------------------------------------------------------------
// Inverse DFT matrix TI[l][r], l in [0,512), r in [0,128):
//  r==0 -> 1/512 ; 1<=r<64 -> 2cos(2*pi*r*l/512)/512 ; r==64 -> 0 ;
//  r>64 -> -2sin(2*pi*(r-64)*l/512)/512.  (numpy irfft, modes 0..63)
// ---------------------------------------------------------------------------
__global__ void irdft_tw_gen(u16* __restrict__ tih)
{
    int idx = blockIdx.x * 256 + threadIdx.x;
    if (idx >= 512 * 128) return;
    int l = idx >> 7, r = idx & 127;
    int m = r & 63;
    int ph = (m * l) & 511;
    float ang = 6.283185307179586f * (float)ph / 512.0f;
    float s_, c_;
    sincosf(ang, &s_, &c_);
    float val;
    if (r == 0) val = 1.0f / 512.0f;
    else if (r < 64) val = 2.0f * c_ / 512.0f;
    else if (r == 64) val = 0.0f;
    else val = -2.0f * s_ / 512.0f;
    tih[idx] = f2h(val);
}

// ---------------------------------------------------------------------------
// Transpose+cast x[b][l][d] fp32 -> xT[b][d][l] fp16. 64x64 LDS tiles.
// grid: (64 = lt*8+dt, 16 = b), 256 threads.
// ---------------------------------------------------------------------------
__global__ __launch_bounds__(256) void tr_cast_x(
    const float* __restrict__ x, u16* __restrict__ xt)
{
    __shared__ u16 t[64][72];
    const int b = blockIdx.y;
    const int lt = (blockIdx.x >> 3) * 64, dt = (blockIdx.x & 7) * 64;
    const int tid = threadIdx.x;
#pragma unroll
    for (int rep = 0; rep < 16; ++rep) {
        int idx = tid + rep * 256;
        int row = idx >> 6, col = idx & 63;
        t[row][col] = f2h(x[((size_t)b * kL + lt + row) * kD + dt + col]);
    }
    __syncthreads();
#pragma unroll
    for (int rep = 0; rep < 16; ++rep) {
        int idx = tid + rep * 256;
        int row = idx >> 6, col = idx & 63;
        xt[((size_t)b * kD + dt + row) * kL + lt + col] = t[col][row];
    }
}

// ---------------------------------------------------------------------------
// Spectral transpose for FEB: QF[b][128][512] fp32 -> QTr/QTi [d][b][m] fp32.
// grid: (8 = d-tile, 16 = b), 256 threads.
// ---------------------------------------------------------------------------
__global__ __launch_bounds__(256) void spec_tr(
    const float* __restrict__ QF, float* __restrict__ qtr, float* __restrict__ qti)
{
    __shared__ float t0[64][65], t1[64][65];
    const int b = blockIdx.y;
    const int dt = blockIdx.x * 64;
    const int tid = threadIdx.x;
    const float* QFb = QF + (size_t)b * 128 * 512;
#pragma unroll
    for (int rep = 0; rep < 16; ++rep) {
        int idx = tid + rep * 256;
        int m = idx >> 6, dd = idx & 63;
        t0[m][dd] = QFb[(size_t)m * 512 + dt + dd];
        t1[m][dd] = QFb[(size_t)(64 + m) * 512 + dt + dd];
    }
    __syncthreads();
#pragma unroll
    for (int rep = 0; rep < 16; ++rep) {
        int idx = tid + rep * 256;
        int dd = idx >> 6, m = idx & 63;
        size_t o = ((size_t)(dt + dd) * kB + b) * kM + m;
        qtr[o] = t0[m][dd];
        qti[o] = t1[m][dd];
    }
}

// ---------------------------------------------------------------------------
// FEB per-mode contraction, d-chunked partials.
// ---------------------------------------------------------------------------
__global__ __launch_bounds__(256) void feb_part(
    const float* __restrict__ qtr, const float* __restrict__ qti,
    const float* __restrict__ wr, const float* __restrict__ wi,
    float* __restrict__ part)
{
    __shared__ float sqr[4][16][64], sqi[4][16][64];
    const int eb = blockIdx.x;
    const int ch = blockIdx.y;
    const int tid = threadIdx.x;
    const int mm = tid & 63, ee = tid >> 6;
    const int e = eb * 4 + ee;
    float ar[16], ai[16];
#pragma unroll
    for (int b_ = 0; b_ < 16; ++b_) { ar[b_] = 0.f; ai[b_] = 0.f; }

    const int dbeg = ch * 128, dend = dbeg + 128;
    for (int d0 = dbeg; d0 < dend; d0 += 4) {
        __syncthreads();
#pragma unroll
        for (int rep = 0; rep < 16; ++rep) {
            int idx = tid + rep * 256;
            int m_ = idx & 63, b_ = (idx >> 6) & 15, dd_ = idx >> 10;
            size_t g = ((size_t)(d0 + dd_) * kB + b_) * kM + m_;
            sqr[dd_][b_][m_] = qtr[g];
            sqi[dd_][b_][m_] = qti[g];
        }
        __syncthreads();
#pragma unroll
        for (int dd = 0; dd < 4; ++dd) {
            size_t wofs = ((size_t)(d0 + dd) * kD + e) * kM + mm;
            float wrv = wr[wofs], wiv = wi[wofs];
#pragma unroll
            for (int b_ = 0; b_ < 16; ++b_) {
                float qr = sqr[dd][b_][mm], qi = sqi[dd][b_][mm];
                ar[b_] += qr * wrv - qi * wiv;
                ai[b_] += qr * wiv + qi * wrv;
            }
        }
    }
    float* reg = part + (size_t)(ch * 128 + eb) * 8192;
#pragma unroll
    for (int b_ = 0; b_ < 16; ++b_) {
        reg[(b_ * 64 + mm) * 4 + ee] = ar[b_];
        reg[4096 + (b_ * 64 + mm) * 4 + ee] = ai[b_];
    }
}

// Reduce partials -> OMT fp16 [b][e][r] (r<64 real, r>=64 imag)
__global__ __launch_bounds__(256) void feb_reduce(
    const float* __restrict__ part, u16* __restrict__ OMT)
{
    int idx = blockIdx.x * 256 + threadIdx.x;   // 0..524287
    int m = idx & 63, e = (idx >> 6) & 511, b = idx >> 15;
    int eb = e >> 2, ee = e & 3;
    float r = 0.f, im = 0.f;
#pragma unroll
    for (int ch = 0; ch < 4; ++ch) {
        const float* reg = part + (size_t)(ch * 128 + eb) * 8192 + ((b * 64 + m) * 4 + ee);
        r += reg[0];
        im += reg[4096];
    }
    u16* o = OMT + ((size_t)(b * 512 + e)) * 128;
    o[m] = f2h(r);
    o[64 + m] = f2h(im);
}

// ---------------------------------------------------------------------------
// Spectral cross attention, one block per (b,h). Inputs QF/KF/VF fp32
// [b][128][512] (rows 0..63 real, 64..127 imag). Output OMT fp16 [b][e][r].
// ---------------------------------------------------------------------------
__global__ __launch_bounds__(256) void spectral_attn(
    const float* __restrict__ QF, const float* __restrict__ KF,
    const float* __restrict__ VF, u16* __restrict__ OMT)
{
    __shared__ float kr[64][65], ki[64][65], sat[64][65];
    const int b = blockIdx.x >> 3, h = blockIdx.x & 7;
    const int tid = threadIdx.x;
    const int dbase = h * 64;
    const float* KFb = KF + (size_t)b * 128 * 512;

    for (int idx = tid; idx < 4096; idx += 256) {
        int j = idx >> 6, dd = idx & 63;
        kr[j][dd] = KFb[(size_t)j * 512 + dbase + dd];
        ki[j][dd] = KFb[(size_t)(64 + j) * 512 + dbase + dd];
    }
    __syncthreads();

    const int i_ = tid >> 2, jg = tid & 3;
    float s[16];
#pragma unroll
    for (int jj = 0; jj < 16; ++jj) s[jj] = 0.f;
    const float* qrp = QF + ((size_t)b * 128 + i_) * 512 + dbase;
    const float* qip = qrp + (size_t)64 * 512;
    for (int dd = 0; dd < 64; ++dd) {
        float qr = qrp[dd], qi = qip[dd];
#pragma unroll
        for (int jj = 0; jj < 16; ++jj) {
            int j = jg * 16 + jj;
            s[jj] += qr * kr[j][dd] + qi * ki[j][dd];
        }
    }
    float mx = s[0];
#pragma unroll
    for (int jj = 1; jj < 16; ++jj) mx = fmaxf(mx, s[jj]);
    mx = fmaxf(mx, __shfl_xor(mx, 1));
    mx = fmaxf(mx, __shfl_xor(mx, 2));
    float sum = 0.f;
#pragma unroll
    for (int jj = 0; jj < 16; ++jj) { s[jj] = expf(s[jj] - mx); sum += s[jj]; }
    sum += __shfl_xor(sum, 1);
    sum += __shfl_xor(sum, 2);
    float rinv = 1.0f / sum;
#pragma unroll
    for (int jj = 0; jj < 16; ++jj) sat[i_][jg * 16 + jj] = s[jj] * rinv;
    __syncthreads();

    const int dd = tid & 63, ig = tid >> 6;
    float ar[16], ai[16];
#pragma unroll
    for (int ii = 0; ii < 16; ++ii) { ar[ii] = 0.f; ai[ii] = 0.f; }
    const float* VFb = VF + (size_t)b * 128 * 512 + dbase + dd;
    for (int j = 0; j < 64; ++j) {
        float vr = VFb[(size_t)j * 512];
        float vi = VFb[(size_t)(64 + j) * 512];
#pragma unroll
        for (int ii = 0; ii < 16; ++ii) {
            float a = sat[ig * 16 + ii][j];
            ar[ii] += a * vr;
            ai[ii] += a * vi;
        }
    }
    // OMT[b][e=dbase+dd][r]: real rows ig*16+ii, imag rows 64+ig*16+ii
    u16* o = OMT + ((size_t)(b * 512 + dbase + dd)) * 128 + ig * 16;
    u16x8 v0, v1, w0, w1;
#pragma unroll
    for (int q = 0; q < 8; ++q) {
        v0[q] = (short)f2h(ar[q]);     v1[q] = (short)f2h(ar[8 + q]);
        w0[q] = (short)f2h(ai[q]);     w1[q] = (short)f2h(ai[8 + q]);
    }
    *(u16x8*)(o) = v0;
    *(u16x8*)(o + 8) = v1;
    *(u16x8*)(o + 64) = w0;
    *(u16x8*)(o + 72) = w1;
}

// ---------------------------------------------------------------------------
// MoE decomposition epilogue: gate softmax + 3 avgpools + mix + subtract.
// ---------------------------------------------------------------------------
__global__ __launch_bounds__(256) void decomp_apply(
    const float* __restrict__ x, const float* __restrict__ logits,
    float* __restrict__ xout, u16* __restrict__ xout_h, u16* __restrict__ tout_h)
{
    int idx = blockIdx.x * 256 + threadIdx.x;
    if (idx >= kB * kL * kD) return;
    int d = idx & 511;
    int l = (idx >> 9) & 511;
    int b = idx >> 18;
    const float* lg = logits + ((size_t)b * kL + l) * 3;
    float g0 = lg[0], g1 = lg[1], g2 = lg[2];
    float m = fmaxf(g0, fmaxf(g1, g2));
    float e0 = expf(g0 - m), e1 = expf(g1 - m), e2 = expf(g2 - m);
    float inv = 1.0f / (e0 + e1 + e2);
    g0 = e0 * inv; g1 = e1 * inv; g2 = e2 * inv;

    const float* xb = x + (size_t)b * kL * kD + d;
    float v[7];
#pragma unroll
    for (int j = 0; j < 7; ++j) {
        int ls = l + j - 3;
        v[j] = (ls >= 0 && ls < kL) ? xb[(size_t)ls * kD] : 0.f;
    }
    float s3 = (v[2] + v[3] + v[4]) * (1.0f / 3.0f);
    float s5 = (v[1] + v[2] + v[3] + v[4] + v[5]) * 0.2f;
    float s7 = (v[0] + v[1] + v[2] + v[3] + v[4] + v[5] + v[6]) * (1.0f / 7.0f);
    float trend = g0 * s3 + g1 * s5 + g2 * s7;
    float res = v[3] - trend;
    if (xout) xout[idx] = res;
    if (xout_h) xout_h[idx] = f2h(res);
    tout_h[idx] = f2h(trend);
}

// ---------------------------------------------------------------------------
// Gate layer 2: logits[r][n] = b2[n] + sum_c GH[r,c]*w2[n,c]  (N=3, K=256)
// ---------------------------------------------------------------------------
__global__ __launch_bounds__(256) void gate2(
    const u16* __restrict__ GH, const float* __restrict__ w2,
    const float* __restrict__ b2, float* __restrict__ logits)
{
    __shared__ float w2l[3][256];
    int tid = threadIdx.x;
    for (int i = tid; i < 768; i += 256) w2l[i >> 8][i & 255] = w2[i];
    __syncthreads();
    int r = blockIdx.x * 256 + tid;
    float s0 = b2[0], s1 = b2[1], s2 = b2[2];
    const u16* g = GH + (size_t)r * 256;
    for (int c0 = 0; c0 < 256; c0 += 8) {
        uint4 u = *(const uint4*)&g[c0];
        u32 w[4] = {u.x, u.y, u.z, u.w};
#pragma unroll
        for (int p = 0; p < 4; ++p) {
            float f0 = h2f((u16)(w[p] & 0xFFFF));
            float f1 = h2f((u16)(w[p] >> 16));
            int c = c0 + p * 2;
            s0 += f0 * w2l[0][c] + f1 * w2l[0][c + 1];
            s1 += f0 * w2l[1][c] + f1 * w2l[1][c + 1];
            s2 += f0 * w2l[2][c] + f1 * w2l[2][c + 1];
        }
    }
    logits[(size_t)r * 3 + 0] = s0;
    logits[(size_t)r * 3 + 1] = s1;
    logits[(size_t)r * 3 + 2] = s2;
}

// ---------------------------------------------------------------------------
__global__ void cast_f32_f16(const float* __restrict__ src, u16* __restrict__ dst, int n)
{
    int idx = (blockIdx.x * 256 + threadIdx.x) * 4;
    if (idx >= n) return;
    float4 v = *(const float4*)&src[idx];
    ushort4 o;
    o.x = f2h(v.x); o.y = f2h(v.y); o.z = f2h(v.z); o.w = f2h(v.w);
    *(ushort4*)&dst[idx] = o;
}

// Repack conv weights p[o,d,j] (fp32) -> pk[t][j][o][d] (fp16)
__global__ void repack_p(const float* __restrict__ p1, const float* __restrict__ p2,
                         const float* __restrict__ p3, u16* __restrict__ pk)
{
    int idx = blockIdx.x * 256 + threadIdx.x;
    if (idx >= 3 * 3 * 512 * 512) return;
    int d = idx & 511;
    int oc = (idx >> 9) & 511;
    int j = (idx / (512 * 512)) % 3;
    int t = idx / (3 * 512 * 512);
    const float* p = (t == 0) ? p1 : (t == 1) ? p2 : p3;
    pk[idx] = f2h(p[(size_t)oc * 512 * 3 + (size_t)d * 3 + j]);
}

// ---------------------------------------------------------------------------
extern "C" void kernel_launch(void* const* d_in, const int* in_sizes, int n_in,
                              void* d_out, int out_size, void* d_ws, size_t ws_size,
                              hipStream_t stream)
{
    const float* x_in   = (const float*)d_in[0];
    const float* cross  = (const float*)d_in[1];
    const float* feb_wr = (const float*)d_in[2];
    const float* feb_wi = (const float*)d_in[3];
    const float* wq = (const float*)d_in[4];
    const float* bq = (const float*)d_in[5];
    const float* wk = (const float*)d_in[6];
    const float* bk = (const float*)d_in[7];
    const float* wv = (const float*)d_in[8];
    const float* bv = (const float*)d_in[9];
    const float* wo = (const float*)d_in[10];
    const float* bo = (const float*)d_in[11];
    const float* w_ff1 = (const float*)d_in[12];
    const float* w_ff2 = (const float*)d_in[13];
    const float* d1_w1 = (const float*)d_in[14];
    const float* d1_b1 = (const float*)d_in[15];
    const float* d1_w2 = (const float*)d_in[16];
    const float* d1_b2 = (const float*)d_in[17];
    const float* d2_w1 = (const float*)d_in[18];
    const float* d2_b1 = (const float*)d_in[19];
    const float* d2_w2 = (const float*)d_in[20];
    const float* d2_b2 = (const float*)d_in[21];
    const float* d3_w1 = (const float*)d_in[22];
    const float* d3_b1 = (const float*)d_in[23];
    const float* d3_w2 = (const float*)d_in[24];
    const float* d3_b2 = (const float*)d_in[25];
    const float* p1 = (const float*)d_in[26];
    const float* p2 = (const float*)d_in[27];
    const float* p3 = (const float*)d_in[28];

    // workspace (float offsets); end ~42.43M floats = 169.7 MB
    float* ws = (float*)d_ws;
    float* X    = ws;                      // 4,194,304
    float* XT   = ws + 4194304;            // 4,194,304
    u16*  Kt    = (u16*)(ws + 8388608);    // [16][512][1024] u16 = 4,194,304 f
    u16*  Vt    = (u16*)(ws + 12582912);   // [16][512][1024] u16 = 4,194,304 f
    u16*  Q0t   = (u16*)(ws + 16777216);   // [16][512][512] u16 = 2,097,152 f
    u16*  T1h   = (u16*)(ws + 18874368);   // 2,097,152 f each; T1,T2,T3 contiguous
    u16*  T2h   = (u16*)(ws + 20971520);
    u16*  T3h   = (u16*)(ws + 23068672);
    float* QF   = ws + 25165824;           // [16][128][512] f32 = 1,048,576
    float* KF   = ws + 26214400;           // 1,048,576
    float* VF   = ws + 27262976;           // 1,048,576
    u16*  OMTh  = (u16*)(ws + 28311552);   // [16][512][128] u16 = 524,288 f
    float* QTr  = ws + 28835840;           // [512][16][64] = 524,288
    float* QTi  = ws + 29360128;           // 524,288
    u16*  crossh = (u16*)(ws + 29884416);  // [16384][512] u16 = 4,194,304 f
    u16*  Xh    = (u16*)(ws + 34078720);   // 2,097,152 f
    u16*  XTh   = (u16*)(ws + 36175872);   // 2,097,152 f
    u16*  GHh   = (u16*)(ws + 38273024);   // 1,048,576 f
    float* GLG  = ws + 39321600;           // 24,576
    u16*  wqh   = (u16*)(ws + 39346176);   // weights fp16 block
    u16*  wkh   = wqh + 262144;
    u16*  wvh   = wkh + 262144;
    u16*  woh   = wvh + 262144;
    u16*  ff1h  = woh + 262144;            // 1,048,576 u16
    u16*  ff2h  = ff1h + 1048576;
    u16*  d1w1h = ff2h + 1048576;          // 131,072 u16 each
    u16*  d2w1h = d1w1h + 131072;
    u16*  d3w1h = d2w1h + 131072;
    u16*  PKh   = d3w1h + 131072;          // 2,359,296 u16
    u16*  TW512h  = (u16*)(ws + 42295296); // 128*512 u16 = 32,768 f
    u16*  TW1024h = (u16*)(ws + 42328064); // 128*1024 u16 = 65,536 f
    u16*  TIh     = (u16*)(ws + 42393600); // 512*128 u16 = 32,768 f
    // overlays:
    float* FEBP = (float*)Kt;              // phase A partials (4,194,304 f)
    u16*  xTh   = Vt;                      // phase A x-transpose ([16][512][512] u16)
    u16*  HIDh  = Kt;                      // phase E hidden (16,777,216 u16 = Kt+Vt)
    u16*  Qh    = Q0t;                     // phase C post-attn overlay

    float* outx = (float*)d_out;
    float* outt = outx + 4194304;

    auto gemm = [&](const u16* A, const u16* W, const float* bias, const float* resid,
                    float* C, u16* Cb, int R, int N, int K, int flags,
                    int Z, u64 zsW, u64 zsC, u64 zsR, int lrsh) {
        dim3 g(N / 128, R / 128, Z);
        hipLaunchKernelGGL(gemm_fp16, g, dim3(256), 0, stream,
                           A, W, bias, resid, C, Cb, R, N, K, flags, zsW, zsC, zsR, lrsh);
    };
    auto cast = [&](const float* s, u16* d, int n) {
        hipLaunchKernelGGL(cast_f32_f16, dim3(n / 1024), dim3(256), 0, stream, s, d, n);
    };

    // ---- Prep: weight casts, twiddle matrices, conv repack ----
    cast(wq, wqh, 262144);
    cast(wk, wkh, 262144);
    cast(wv, wvh, 262144);
    cast(wo, woh, 262144);
    cast(w_ff1, ff1h, 1048576);
    cast(w_ff2, ff2h, 1048576);
    cast(d1_w1, d1w1h, 131072);
    cast(d2_w1, d2w1h, 131072);
    cast(d3_w1, d3w1h, 131072);
    cast(cross, crossh, 8388608);
    hipLaunchKernelGGL(dft_tw_gen, dim3(256), dim3(256), 0, stream, TW512h, 512);
    hipLaunchKernelGGL(dft_tw_gen, dim3(512), dim3(256), 0, stream, TW1024h, 1024);
    hipLaunchKernelGGL(irdft_tw_gen, dim3(256), dim3(256), 0, stream, TIh);
    hipLaunchKernelGGL(repack_p, dim3(9216), dim3(256), 0, stream, p1, p2, p3, PKh);

    // ---- Phase A: x = x + fourier_block(x) ----
    hipLaunchKernelGGL(tr_cast_x, dim3(64, 16), dim3(256), 0, stream, x_in, xTh);
    gemm(TW512h, xTh, nullptr, nullptr, QF, nullptr, 128, 512, 512, 16,
         16, (u64)512 * 512, (u64)128 * 512, 0, 0);
    hipLaunchKernelGGL(spec_tr, dim3(8, 16), dim3(256), 0, stream, QF, QTr, QTi);
    hipLaunchKernelGGL(feb_part, dim3(128, 4), dim3(256), 0, stream, QTr, QTi, feb_wr, feb_wi, FEBP);
    hipLaunchKernelGGL(feb_reduce, dim3(2048), dim3(256), 0, stream, FEBP, OMTh);
    gemm(TIh, OMTh, nullptr, x_in, X, Xh, 512, 512, 128, 16 | 8,
         16, (u64)512 * 128, (u64)512 * 512, (u64)512 * 512, 0);

    // ---- Phase B: decomp1 ----
    gemm(Xh, d1w1h, d1_b1, nullptr, nullptr, GHh, 8192, 256, 512, 1 | 8, 1, 0, 0, 0, 0);
    hipLaunchKernelGGL(gate2, dim3(32), dim3(256), 0, stream, GHh, d1_w2, d1_b2, GLG);
    hipLaunchKernelGGL(decomp_apply, dim3(16384), dim3(256), 0, stream, X, GLG, XT, XTh, T1h);

    // ---- Phase C: x = x + fourier_cross(x, cross) ----
    gemm(XTh, wqh, bq, nullptr, nullptr, Q0t, 8192, 512, 512, 32, 1, 0, 0, 0, 9);
    gemm(crossh, wkh, bk, nullptr, nullptr, Kt, 16384, 512, 512, 32, 1, 0, 0, 0, 10);
    gemm(crossh, wvh, bv, nullptr, nullptr, Vt, 16384, 512, 512, 32, 1, 0, 0, 0, 10);
    gemm(TW512h, Q0t, nullptr, nullptr, QF, nullptr, 128, 512, 512, 16,
         16, (u64)512 * 512, (u64)128 * 512, 0, 0);
    gemm(TW1024h, Kt, nullptr, nullptr, KF, nullptr, 128, 512, 1024, 16,
         16, (u64)512 * 1024, (u64)128 * 512, 0, 0);
    gemm(TW1024h, Vt, nullptr, nullptr, VF, nullptr, 128, 512, 1024, 16,
         16, (u64)512 * 1024, (u64)128 * 512, 0, 0);
    hipLaunchKernelGGL(spectral_attn, dim3(128), dim3(256), 0, stream, QF, KF, VF, OMTh);
    gemm(TIh, OMTh, nullptr, nullptr, nullptr, Qh, 512, 512, 128, 8,
         16, (u64)512 * 128, (u64)512 * 512, 0, 0);
    gemm(Qh, woh, bo, XT, X, Xh, 8192, 512, 512, 16 | 8, 1, 0, 0, 0, 0);

    // ---- Phase D: decomp2 ----
    gemm(Xh, d2w1h, d2_b1, nullptr, nullptr, GHh, 8192, 256, 512, 1 | 8, 1, 0, 0, 0, 0);
    hipLaunchKernelGGL(gate2, dim3(32), dim3(256), 0, stream, GHh, d2_w2, d2_b2, GLG);
    hipLaunchKernelGGL(decomp_apply, dim3(16384), dim3(256), 0, stream, X, GLG, XT, XTh, T2h);

    // ---- Phase E: FFN ----
    gemm(XTh, ff1h, nullptr, nullptr, nullptr, HIDh, 8192, 2048, 512, 1 | 8, 1, 0, 0, 0, 0);
    gemm(HIDh, ff2h, nullptr, XT, X, Xh, 8192, 512, 2048, 16 | 8, 1, 0, 0, 0, 0);

    // ---- Phase F: decomp3 -> d_out x ----
    gemm(Xh, d3w1h, d3_b1, nullptr, nullptr, GHh, 8192, 256, 512, 1 | 8, 1, 0, 0, 0, 0);
    hipLaunchKernelGGL(gate2, dim3(32), dim3(256), 0, stream, GHh, d3_w2, d3_b2, GLG);
    hipLaunchKernelGGL(decomp_apply, dim3(16384), dim3(256), 0, stream, X, GLG, outx,
                       (u16*)nullptr, T3h);

    // ---- Phase G: residual_trend, one K=4608 fp16 GEMM over (t,j) ----
    gemm(T1h, PKh, nullptr, nullptr, outt, nullptr, 8192, 512, 4608, 4 | 16, 1, 0, 0, 0, 0);

    (void)in_sizes; (void)n_in; (void)out_size; (void)ws_size;
}

// Round 6
// 596.358 us; speedup vs baseline: 2.6116x; 1.2914x over previous
//
#include <hip/hip_runtime.h>
#include <math.h>

typedef unsigned short u16;
typedef unsigned int u32;
typedef unsigned long long u64;

constexpr int kB = 16, kL = 512, kS = 1024, kD = 512, kM = 64;

typedef __attribute__((ext_vector_type(8))) short u16x8;
typedef __attribute__((ext_vector_type(8))) _Float16 f16x8;
typedef __attribute__((ext_vector_type(4))) float f32x4;

__device__ __forceinline__ u16 f2h(float f) {
    _Float16 h = (_Float16)f;
    return *(u16*)&h;
}
__device__ __forceinline__ float h2f(u16 u) {
    _Float16 h = *(_Float16*)&u;
    return (float)h;
}

// ---------------------------------------------------------------------------
// fp16 MFMA GEMM, z-batched: C[z][r,n] = op( sum_k A[z][r,k]*W[z][n,k] + .. )
// A: R x K fp16 row-major; W: N x K fp16 rows (X @ W.T). 128x128 tile, BK=64.
// flags: 1=relu, 8=write fp16 Ch[r][n], 16=write f32 Cout[r][n],
//        32=write fp16 transposed Ch[b][n][l], b=r>>lrsh, l=r&((1<<lrsh)-1)
// ---------------------------------------------------------------------------
__global__ __launch_bounds__(256, 4) void gemm_fp16(
    const u16* __restrict__ Abase, const u16* __restrict__ Wbase,
    const float* __restrict__ bias, const float* __restrict__ resid,
    float* __restrict__ Cout, u16* __restrict__ Ch,
    int R, int N, int K, int flags,
    u64 zsA, u64 zsW, u64 zsC, u64 zsR, int lrsh)
{
    __shared__ __attribute__((aligned(16))) u16 Abuf[128 * 64];
    __shared__ __attribute__((aligned(16))) u16 Bbuf[128 * 64];
    const int zz = blockIdx.z;
    Abase += (u64)zz * zsA;
    Wbase += (u64)zz * zsW;
    if (Cout) Cout += (u64)zz * zsC;
    if (Ch)   Ch   += (u64)zz * zsC;
    if (resid) resid += (u64)zz * zsR;

    const int tid = threadIdx.x;
    const int lane = tid & 63;
    const int wave = tid >> 6;
    const int wr = wave >> 1, wc = wave & 1;
    const int ln15 = lane & 15, lq = lane >> 4;
    const int r0 = blockIdx.y * 128, n0 = blockIdx.x * 128;

    f32x4 acc[4][4];
#pragma unroll
    for (int m = 0; m < 4; ++m)
#pragma unroll
        for (int n = 0; n < 4; ++n) acc[m][n] = (f32x4){0.f, 0.f, 0.f, 0.f};

    for (int k0 = 0; k0 < K; k0 += 64) {
        u16x8 av[4], bv[4];
#pragma unroll
        for (int it = 0; it < 4; ++it) {
            int c = it * 256 + tid;
            int row = c >> 3, j = c & 7;
            int jj = j ^ (row & 7);
            av[it] = *(const u16x8*)(Abase + (size_t)(r0 + row) * K + k0 + jj * 8);
            bv[it] = *(const u16x8*)(Wbase + (size_t)(n0 + row) * K + k0 + jj * 8);
        }
        __syncthreads();
#pragma unroll
        for (int it = 0; it < 4; ++it) {
            int c = it * 256 + tid;
            int row = c >> 3, j = c & 7;
            *(u16x8*)&Abuf[row * 64 + j * 8] = av[it];
            *(u16x8*)&Bbuf[row * 64 + j * 8] = bv[it];
        }
        __syncthreads();
#pragma unroll
        for (int h = 0; h < 2; ++h) {
            int kg = lq + h * 4;
            f16x8 af[4], bfv[4];
#pragma unroll
            for (int m = 0; m < 4; ++m) {
                int row = wr * 64 + m * 16 + ln15;
                af[m] = *(const f16x8*)&Abuf[row * 64 + ((kg ^ (row & 7)) << 3)];
            }
#pragma unroll
            for (int n = 0; n < 4; ++n) {
                int col = wc * 64 + n * 16 + ln15;
                bfv[n] = *(const f16x8*)&Bbuf[col * 64 + ((kg ^ (col & 7)) << 3)];
            }
#pragma unroll
            for (int m = 0; m < 4; ++m)
#pragma unroll
                for (int n = 0; n < 4; ++n)
                    acc[m][n] = __builtin_amdgcn_mfma_f32_16x16x32_f16(af[m], bfv[n], acc[m][n], 0, 0, 0);
        }
        __syncthreads();
    }

#pragma unroll
    for (int m = 0; m < 4; ++m) {
#pragma unroll
        for (int n = 0; n < 4; ++n) {
            int gc = n0 + wc * 64 + n * 16 + ln15;
            float bv_ = bias ? bias[gc] : 0.f;
            int gr0 = r0 + wr * 64 + m * 16 + lq * 4;
            float v[4];
#pragma unroll
            for (int rg = 0; rg < 4; ++rg) {
                int gr = gr0 + rg;
                float val = acc[m][n][rg] + bv_;
                if (resid) val += resid[(size_t)gr * N + gc];
                if (flags & 1) val = fmaxf(val, 0.f);
                if (flags & 16) Cout[(size_t)gr * N + gc] = val;
                if (flags & 8)  Ch[(size_t)gr * N + gc] = f2h(val);
                v[rg] = val;
            }
            if (flags & 32) {
                int bb = gr0 >> lrsh;
                int l_ = gr0 & ((1 << lrsh) - 1);
                ushort4 o;
                o.x = f2h(v[0]); o.y = f2h(v[1]); o.z = f2h(v[2]); o.w = f2h(v[3]);
                *(ushort4*)&Ch[(((size_t)bb * N + gc) << lrsh) + l_] = o;
            }
        }
    }
}

// ---------------------------------------------------------------------------
// 64x64-tile fp16 GEMM for thin/batched shapes. 4 waves; wave w does
// 64 rows x cols [w*16, w*16+16) via 4 stacked 16x16x32 frags. BK=64.
// flags: 1=relu, 8=fp16 Ch, 16=f32 Cout.
// ---------------------------------------------------------------------------
__global__ __launch_bounds__(256, 4) void gemm64(
    const u16* __restrict__ Abase, const u16* __restrict__ Wbase,
    const float* __restrict__ bias, const float* __restrict__ resid,
    float* __restrict__ Cout, u16* __restrict__ Ch,
    int R, int N, int K, int flags,
    u64 zsA, u64 zsW, u64 zsC, u64 zsR)
{
    __shared__ __attribute__((aligned(16))) u16 Abuf[64 * 64];
    __shared__ __attribute__((aligned(16))) u16 Bbuf[64 * 64];
    const int zz = blockIdx.z;
    Abase += (u64)zz * zsA;
    Wbase += (u64)zz * zsW;
    if (Cout) Cout += (u64)zz * zsC;
    if (Ch)   Ch   += (u64)zz * zsC;
    if (resid) resid += (u64)zz * zsR;

    const int tid = threadIdx.x;
    const int lane = tid & 63;
    const int w = tid >> 6;
    const int ln15 = lane & 15, lq = lane >> 4;
    const int r0 = blockIdx.y * 64, n0 = blockIdx.x * 64;

    f32x4 acc[4];
#pragma unroll
    for (int m = 0; m < 4; ++m) acc[m] = (f32x4){0.f, 0.f, 0.f, 0.f};

    for (int k0 = 0; k0 < K; k0 += 64) {
        u16x8 av[2], bv[2];
#pragma unroll
        for (int it = 0; it < 2; ++it) {
            int c = it * 256 + tid;
            int row = c >> 3, j = c & 7;
            int jj = j ^ (row & 7);
            av[it] = *(const u16x8*)(Abase + (size_t)(r0 + row) * K + k0 + jj * 8);
            bv[it] = *(const u16x8*)(Wbase + (size_t)(n0 + row) * K + k0 + jj * 8);
        }
        __syncthreads();
#pragma unroll
        for (int it = 0; it < 2; ++it) {
            int c = it * 256 + tid;
            int row = c >> 3, j = c & 7;
            *(u16x8*)&Abuf[row * 64 + j * 8] = av[it];
            *(u16x8*)&Bbuf[row * 64 + j * 8] = bv[it];
        }
        __syncthreads();
#pragma unroll
        for (int h = 0; h < 2; ++h) {
            int kg = lq + h * 4;
            int col = w * 16 + ln15;
            f16x8 bf = *(const f16x8*)&Bbuf[col * 64 + ((kg ^ (col & 7)) << 3)];
#pragma unroll
            for (int m = 0; m < 4; ++m) {
                int row = m * 16 + ln15;
                f16x8 af = *(const f16x8*)&Abuf[row * 64 + ((kg ^ (row & 7)) << 3)];
                acc[m] = __builtin_amdgcn_mfma_f32_16x16x32_f16(af, bf, acc[m], 0, 0, 0);
            }
        }
        __syncthreads();
    }

    const int gc = n0 + w * 16 + ln15;
    const float bv_ = bias ? bias[gc] : 0.f;
#pragma unroll
    for (int m = 0; m < 4; ++m) {
        int gr0 = r0 + m * 16 + lq * 4;
#pragma unroll
        for (int rg = 0; rg < 4; ++rg) {
            int gr = gr0 + rg;
            float val = acc[m][rg] + bv_;
            if (resid) val += resid[(size_t)gr * N + gc];
            if (flags & 1) val = fmaxf(val, 0.f);
            if (flags & 16) Cout[(size_t)gr * N + gc] = val;
            if (flags & 8)  Ch[(size_t)gr * N + gc] = f2h(val);
        }
    }
}

// ---------------------------------------------------------------------------
// Fused prep: all weight casts, K|V weight/bias concat, cross cast, twiddles.
// ---------------------------------------------------------------------------
__global__ __launch_bounds__(256) void prep(
    const float* __restrict__ wq, const float* __restrict__ wk,
    const float* __restrict__ wv, const float* __restrict__ wo,
    const float* __restrict__ ff1, const float* __restrict__ ff2,
    const float* __restrict__ dw1, const float* __restrict__ dw2,
    const float* __restrict__ dw3, const float* __restrict__ cross,
    const float* __restrict__ bk, const float* __restrict__ bv,
    u16* __restrict__ wqh, u16* __restrict__ wkvh, u16* __restrict__ woh,
    u16* __restrict__ ff1h, u16* __restrict__ ff2h,
    u16* __restrict__ d1w1h, u16* __restrict__ d2w1h, u16* __restrict__ d3w1h,
    u16* __restrict__ crossh, float* __restrict__ bkv,
    u16* __restrict__ tw512, u16* __restrict__ tw1024, u16* __restrict__ tih)
{
    const int gid = blockIdx.x * 256 + threadIdx.x;
    const int stride = gridDim.x * 256;
    for (int i = gid; i < 262144; i += stride) wqh[i] = f2h(wq[i]);
    for (int i = gid; i < 262144; i += stride) wkvh[i] = f2h(wk[i]);
    for (int i = gid; i < 262144; i += stride) wkvh[262144 + i] = f2h(wv[i]);
    for (int i = gid; i < 262144; i += stride) woh[i] = f2h(wo[i]);
    for (int i = gid; i < 1048576; i += stride) ff1h[i] = f2h(ff1[i]);
    for (int i = gid; i < 1048576; i += stride) ff2h[i] = f2h(ff2[i]);
    for (int i = gid; i < 131072; i += stride) d1w1h[i] = f2h(dw1[i]);
    for (int i = gid; i < 131072; i += stride) d2w1h[i] = f2h(dw2[i]);
    for (int i = gid; i < 131072; i += stride) d3w1h[i] = f2h(dw3[i]);
    const float4* c4 = (const float4*)cross;
    for (int i = gid; i < 2097152; i += stride) {
        float4 v = c4[i];
        ushort4 o;
        o.x = f2h(v.x); o.y = f2h(v.y); o.z = f2h(v.z); o.w = f2h(v.w);
        *(ushort4*)&crossh[i * 4] = o;
    }
    for (int i = gid; i < 1024; i += stride) bkv[i] = (i < 512) ? bk[i] : bv[i - 512];
    // forward twiddles, N=512: tw[r*512+l]
    for (int i = gid; i < 65536; i += stride) {
        int r = i >> 9, l = i & 511;
        int m = r & 63;
        int ph = (m * l) & 511;
        float ang = 6.283185307179586f * (float)ph / 512.0f;
        float s_, c_;
        sincosf(ang, &s_, &c_);
        tw512[i] = f2h((r < 64) ? c_ : -s_);
    }
    // forward twiddles, N=1024
    for (int i = gid; i < 131072; i += stride) {
        int r = i >> 10, l = i & 1023;
        int m = r & 63;
        int ph = (m * l) & 1023;
        float ang = 6.283185307179586f * (float)ph / 1024.0f;
        float s_, c_;
        sincosf(ang, &s_, &c_);
        tw1024[i] = f2h((r < 64) ? c_ : -s_);
    }
    // inverse matrix TI[l][r]
    for (int i = gid; i < 65536; i += stride) {
        int l = i >> 7, r = i & 127;
        int m = r & 63;
        int ph = (m * l) & 511;
        float ang = 6.283185307179586f * (float)ph / 512.0f;
        float s_, c_;
        sincosf(ang, &s_, &c_);
        float val;
        if (r == 0) val = 1.0f / 512.0f;
        else if (r < 64) val = 2.0f * c_ / 512.0f;
        else if (r == 64) val = 0.0f;
        else val = -2.0f * s_ / 512.0f;
        tih[i] = f2h(val);
    }
}

// ---------------------------------------------------------------------------
// Transpose+cast x[b][l][d] fp32 -> xT[b][d][l] fp16. 64x64 LDS tiles.
// ---------------------------------------------------------------------------
__global__ __launch_bounds__(256) void tr_cast_x(
    const float* __restrict__ x, u16* __restrict__ xt)
{
    __shared__ u16 t[64][72];
    const int b = blockIdx.y;
    const int lt = (blockIdx.x >> 3) * 64, dt = (blockIdx.x & 7) * 64;
    const int tid = threadIdx.x;
#pragma unroll
    for (int rep = 0; rep < 16; ++rep) {
        int idx = tid + rep * 256;
        int row = idx >> 6, col = idx & 63;
        t[row][col] = f2h(x[((size_t)b * kL + lt + row) * kD + dt + col]);
    }
    __syncthreads();
#pragma unroll
    for (int rep = 0; rep < 16; ++rep) {
        int idx = tid + rep * 256;
        int row = idx >> 6, col = idx & 63;
        xt[((size_t)b * kD + dt + row) * kL + lt + col] = t[col][row];
    }
}

// ---------------------------------------------------------------------------
// Spectral transpose for FEB: QF[b][128][512] fp32 -> QTr/QTi [d][b][m] fp32.
// ---------------------------------------------------------------------------
__global__ __launch_bounds__(256) void spec_tr(
    const float* __restrict__ QF, float* __restrict__ qtr, float* __restrict__ qti)
{
    __shared__ float t0[64][65], t1[64][65];
    const int b = blockIdx.y;
    const int dt = blockIdx.x * 64;
    const int tid = threadIdx.x;
    const float* QFb = QF + (size_t)b * 128 * 512;
#pragma unroll
    for (int rep = 0; rep < 16; ++rep) {
        int idx = tid + rep * 256;
        int m = idx >> 6, dd = idx & 63;
        t0[m][dd] = QFb[(size_t)m * 512 + dt + dd];
        t1[m][dd] = QFb[(size_t)(64 + m) * 512 + dt + dd];
    }
    __syncthreads();
#pragma unroll
    for (int rep = 0; rep < 16; ++rep) {
        int idx = tid + rep * 256;
        int dd = idx >> 6, m = idx & 63;
        size_t o = ((size_t)(dt + dd) * kB + b) * kM + m;
        qtr[o] = t0[m][dd];
        qti[o] = t1[m][dd];
    }
}

// ---------------------------------------------------------------------------
// FEB per-mode contraction, d-chunked partials.
// ---------------------------------------------------------------------------
__global__ __launch_bounds__(256) void feb_part(
    const float* __restrict__ qtr, const float* __restrict__ qti,
    const float* __restrict__ wr, const float* __restrict__ wi,
    float* __restrict__ part)
{
    __shared__ float sqr[4][16][64], sqi[4][16][64];
    const int eb = blockIdx.x;
    const int ch = blockIdx.y;
    const int tid = threadIdx.x;
    const int mm = tid & 63, ee = tid >> 6;
    const int e = eb * 4 + ee;
    float ar[16], ai[16];
#pragma unroll
    for (int b_ = 0; b_ < 16; ++b_) { ar[b_] = 0.f; ai[b_] = 0.f; }

    const int dbeg = ch * 128, dend = dbeg + 128;
    for (int d0 = dbeg; d0 < dend; d0 += 4) {
        __syncthreads();
#pragma unroll
        for (int rep = 0; rep < 16; ++rep) {
            int idx = tid + rep * 256;
            int m_ = idx & 63, b_ = (idx >> 6) & 15, dd_ = idx >> 10;
            size_t g = ((size_t)(d0 + dd_) * kB + b_) * kM + m_;
            sqr[dd_][b_][m_] = qtr[g];
            sqi[dd_][b_][m_] = qti[g];
        }
        __syncthreads();
#pragma unroll
        for (int dd = 0; dd < 4; ++dd) {
            size_t wofs = ((size_t)(d0 + dd) * kD + e) * kM + mm;
            float wrv = wr[wofs], wiv = wi[wofs];
#pragma unroll
            for (int b_ = 0; b_ < 16; ++b_) {
                float qr = sqr[dd][b_][mm], qi = sqi[dd][b_][mm];
                ar[b_] += qr * wrv - qi * wiv;
                ai[b_] += qr * wiv + qi * wrv;
            }
        }
    }
    float* reg = part + (size_t)(ch * 128 + eb) * 8192;
#pragma unroll
    for (int b_ = 0; b_ < 16; ++b_) {
        reg[(b_ * 64 + mm) * 4 + ee] = ar[b_];
        reg[4096 + (b_ * 64 + mm) * 4 + ee] = ai[b_];
    }
}

// Reduce partials -> OMT fp16 [b][e][r] (r<64 real, r>=64 imag)
__global__ __launch_bounds__(256) void feb_reduce(
    const float* __restrict__ part, u16* __restrict__ OMT)
{
    int idx = blockIdx.x * 256 + threadIdx.x;   // 0..524287
    int m = idx & 63, e = (idx >> 6) & 511, b = idx >> 15;
    int eb = e >> 2, ee = e & 3;
    float r = 0.f, im = 0.f;
#pragma unroll
    for (int ch = 0; ch < 4; ++ch) {
        const float* reg = part + (size_t)(ch * 128 + eb) * 8192 + ((b * 64 + m) * 4 + ee);
        r += reg[0];
        im += reg[4096];
    }
    u16* o = OMT + ((size_t)(b * 512 + e)) * 128;
    o[m] = f2h(r);
    o[64 + m] = f2h(im);
}

// ---------------------------------------------------------------------------
// Spectral cross attention, one block per (b,h). QF fp32 [b][128][512];
// KVF fp32 [b][128][1024] (cols 0:512 = K-chan, 512:1024 = V-chan;
// rows 0..63 real, 64..127 imag). Output OMT fp16 [b][e][r].
// ---------------------------------------------------------------------------
__global__ __launch_bounds__(256) void spectral_attn(
    const float* __restrict__ QF, const float* __restrict__ KVF,
    u16* __restrict__ OMT)
{
    __shared__ float kr[64][65], ki[64][65], sat[64][65];
    const int b = blockIdx.x >> 3, h = blockIdx.x & 7;
    const int tid = threadIdx.x;
    const int dbase = h * 64;
    const float* KVFb = KVF + (size_t)b * 128 * 1024;

    for (int idx = tid; idx < 4096; idx += 256) {
        int j = idx >> 6, dd = idx & 63;
        kr[j][dd] = KVFb[(size_t)j * 1024 + dbase + dd];
        ki[j][dd] = KVFb[(size_t)(64 + j) * 1024 + dbase + dd];
    }
    __syncthreads();

    const int i_ = tid >> 2, jg = tid & 3;
    float s[16];
#pragma unroll
    for (int jj = 0; jj < 16; ++jj) s[jj] = 0.f;
    const float* qrp = QF + ((size_t)b * 128 + i_) * 512 + dbase;
    const float* qip = qrp + (size_t)64 * 512;
    for (int dd = 0; dd < 64; ++dd) {
        float qr = qrp[dd], qi = qip[dd];
#pragma unroll
        for (int jj = 0; jj < 16; ++jj) {
            int j = jg * 16 + jj;
            s[jj] += qr * kr[j][dd] + qi * ki[j][dd];
        }
    }
    float mx = s[0];
#pragma unroll
    for (int jj = 1; jj < 16; ++jj) mx = fmaxf(mx, s[jj]);
    mx = fmaxf(mx, __shfl_xor(mx, 1));
    mx = fmaxf(mx, __shfl_xor(mx, 2));
    float sum = 0.f;
#pragma unroll
    for (int jj = 0; jj < 16; ++jj) { s[jj] = expf(s[jj] - mx); sum += s[jj]; }
    sum += __shfl_xor(sum, 1);
    sum += __shfl_xor(sum, 2);
    float rinv = 1.0f / sum;
#pragma unroll
    for (int jj = 0; jj < 16; ++jj) sat[i_][jg * 16 + jj] = s[jj] * rinv;
    __syncthreads();

    const int dd = tid & 63, ig = tid >> 6;
    float ar[16], ai[16];
#pragma unroll
    for (int ii = 0; ii < 16; ++ii) { ar[ii] = 0.f; ai[ii] = 0.f; }
    const float* VFb = KVFb + 512 + dbase + dd;
    for (int j = 0; j < 64; ++j) {
        float vr = VFb[(size_t)j * 1024];
        float vi = VFb[(size_t)(64 + j) * 1024];
#pragma unroll
        for (int ii = 0; ii < 16; ++ii) {
            float a = sat[ig * 16 + ii][j];
            ar[ii] += a * vr;
            ai[ii] += a * vi;
        }
    }
    u16* o = OMT + ((size_t)(b * 512 + dbase + dd)) * 128 + ig * 16;
    u16x8 v0, v1, w0, w1;
#pragma unroll
    for (int q = 0; q < 8; ++q) {
        v0[q] = (short)f2h(ar[q]);     v1[q] = (short)f2h(ar[8 + q]);
        w0[q] = (short)f2h(ai[q]);     w1[q] = (short)f2h(ai[8 + q]);
    }
    *(u16x8*)(o) = v0;
    *(u16x8*)(o + 8) = v1;
    *(u16x8*)(o + 64) = w0;
    *(u16x8*)(o + 72) = w1;
}

// ---------------------------------------------------------------------------
// MoE decomposition epilogue.
// ---------------------------------------------------------------------------
__global__ __launch_bounds__(256) void decomp_apply(
    const float* __restrict__ x, const float* __restrict__ logits,
    float* __restrict__ xout, u16* __restrict__ xout_h, u16* __restrict__ tout_h)
{
    int idx = blockIdx.x * 256 + threadIdx.x;
    if (idx >= kB * kL * kD) return;
    int d = idx & 511;
    int l = (idx >> 9) & 511;
    int b = idx >> 18;
    const float* lg = logits + ((size_t)b * kL + l) * 3;
    float g0 = lg[0], g1 = lg[1], g2 = lg[2];
    float m = fmaxf(g0, fmaxf(g1, g2));
    float e0 = expf(g0 - m), e1 = expf(g1 - m), e2 = expf(g2 - m);
    float inv = 1.0f / (e0 + e1 + e2);
    g0 = e0 * inv; g1 = e1 * inv; g2 = e2 * inv;

    const float* xb = x + (size_t)b * kL * kD + d;
    float v[7];
#pragma unroll
    for (int j = 0; j < 7; ++j) {
        int ls = l + j - 3;
        v[j] = (ls >= 0 && ls < kL) ? xb[(size_t)ls * kD] : 0.f;
    }
    float s3 = (v[2] + v[3] + v[4]) * (1.0f / 3.0f);
    float s5 = (v[1] + v[2] + v[3] + v[4] + v[5]) * 0.2f;
    float s7 = (v[0] + v[1] + v[2] + v[3] + v[4] + v[5] + v[6]) * (1.0f / 7.0f);
    float trend = g0 * s3 + g1 * s5 + g2 * s7;
    float res = v[3] - trend;
    if (xout) xout[idx] = res;
    if (xout_h) xout_h[idx] = f2h(res);
    tout_h[idx] = f2h(trend);
}

// ---------------------------------------------------------------------------
// Gate layer 2: logits[r][n] = b2[n] + sum_c GH[r,c]*w2[n,c]  (N=3, K=256)
// ---------------------------------------------------------------------------
__global__ __launch_bounds__(256) void gate2(
    const u16* __restrict__ GH, const float* __restrict__ w2,
    const float* __restrict__ b2, float* __restrict__ logits)
{
    __shared__ float w2l[3][256];
    int tid = threadIdx.x;
    for (int i = tid; i < 768; i += 256) w2l[i >> 8][i & 255] = w2[i];
    __syncthreads();
    int r = blockIdx.x * 256 + tid;
    float s0 = b2[0], s1 = b2[1], s2 = b2[2];
    const u16* g = GH + (size_t)r * 256;
    for (int c0 = 0; c0 < 256; c0 += 8) {
        uint4 u = *(const uint4*)&g[c0];
        u32 w[4] = {u.x, u.y, u.z, u.w};
#pragma unroll
        for (int p = 0; p < 4; ++p) {
            float f0 = h2f((u16)(w[p] & 0xFFFF));
            float f1 = h2f((u16)(w[p] >> 16));
            int c = c0 + p * 2;
            s0 += f0 * w2l[0][c] + f1 * w2l[0][c + 1];
            s1 += f0 * w2l[1][c] + f1 * w2l[1][c + 1];
            s2 += f0 * w2l[2][c] + f1 * w2l[2][c + 1];
        }
    }
    logits[(size_t)r * 3 + 0] = s0;
    logits[(size_t)r * 3 + 1] = s1;
    logits[(size_t)r * 3 + 2] = s2;
}

// Repack conv weights p[o,d,j] (fp32) -> pk[t][j][o][d] (fp16)
__global__ void repack_p(const float* __restrict__ p1, const float* __restrict__ p2,
                         const float* __restrict__ p3, u16* __restrict__ pk)
{
    int idx = blockIdx.x * 256 + threadIdx.x;
    if (idx >= 3 * 3 * 512 * 512) return;
    int d = idx & 511;
    int oc = (idx >> 9) & 511;
    int j = (idx / (512 * 512)) % 3;
    int t = idx / (3 * 512 * 512);
    const float* p = (t == 0) ? p1 : (t == 1) ? p2 : p3;
    pk[idx] = f2h(p[(size_t)oc * 512 * 3 + (size_t)d * 3 + j]);
}

// ---------------------------------------------------------------------------
// Conv epilogue: outt[b][l][oc] = sum_{t,j} Cc[t][b*512+((l+j-1)%512)][j*512+oc]
// ---------------------------------------------------------------------------
__global__ __launch_bounds__(256) void conv_sum(
    const u16* __restrict__ Cc, float* __restrict__ outt)
{
    int gid = blockIdx.x * 256 + threadIdx.x;   // 524288 items
    int ocg = gid & 63;
    int r = gid >> 6;
    int b = r >> 9, l = r & 511;
    float s[8];
#pragma unroll
    for (int q = 0; q < 8; ++q) s[q] = 0.f;
#pragma unroll
    for (int t = 0; t < 3; ++t) {
#pragma unroll
        for (int j = 0; j < 3; ++j) {
            int lr = (l + j + 511) & 511;
            const u16x8 v = *(const u16x8*)&Cc[(size_t)t * 8192 * 1536 +
                ((size_t)(b * 512 + lr)) * 1536 + j * 512 + ocg * 8];
#pragma unroll
            for (int q = 0; q < 8; ++q) s[q] += h2f((u16)v[q]);
        }
    }
    float4 o0 = {s[0], s[1], s[2], s[3]};
    float4 o1 = {s[4], s[5], s[6], s[7]};
    *(float4*)&outt[(size_t)r * 512 + ocg * 8] = o0;
    *(float4*)&outt[(size_t)r * 512 + ocg * 8 + 4] = o1;
}

// ---------------------------------------------------------------------------
extern "C" void kernel_launch(void* const* d_in, const int* in_sizes, int n_in,
                              void* d_out, int out_size, void* d_ws, size_t ws_size,
                              hipStream_t stream)
{
    const float* x_in   = (const float*)d_in[0];
    const float* cross  = (const float*)d_in[1];
    const float* feb_wr = (const float*)d_in[2];
    const float* feb_wi = (const float*)d_in[3];
    const float* wq = (const float*)d_in[4];
    const float* bq = (const float*)d_in[5];
    const float* wk = (const float*)d_in[6];
    const float* bk = (const float*)d_in[7];
    const float* wv = (const float*)d_in[8];
    const float* bv = (const float*)d_in[9];
    const float* wo = (const float*)d_in[10];
    const float* bo = (const float*)d_in[11];
    const float* w_ff1 = (const float*)d_in[12];
    const float* w_ff2 = (const float*)d_in[13];
    const float* d1_w1 = (const float*)d_in[14];
    const float* d1_b1 = (const float*)d_in[15];
    const float* d1_w2 = (const float*)d_in[16];
    const float* d1_b2 = (const float*)d_in[17];
    const float* d2_w1 = (const float*)d_in[18];
    const float* d2_b1 = (const float*)d_in[19];
    const float* d2_w2 = (const float*)d_in[20];
    const float* d2_b2 = (const float*)d_in[21];
    const float* d3_w1 = (const float*)d_in[22];
    const float* d3_b1 = (const float*)d_in[23];
    const float* d3_w2 = (const float*)d_in[24];
    const float* d3_b2 = (const float*)d_in[25];
    const float* p1 = (const float*)d_in[26];
    const float* p2 = (const float*)d_in[27];
    const float* p3 = (const float*)d_in[28];

    // workspace (float offsets); end 42,427,392 floats = 169.7 MB
    float* ws = (float*)d_ws;
    float* X    = ws;                      // 4,194,304
    float* XT   = ws + 4194304;            // 4,194,304
    u16*  KVt   = (u16*)(ws + 8388608);    // [16][1024][1024] u16 = 8,388,608 f
    u16*  Q0t   = (u16*)(ws + 16777216);   // [16][512][512] u16 = 2,097,152 f
    u16*  T1h   = (u16*)(ws + 18874368);   // 2,097,152 f each; T1,T2,T3 contiguous
    u16*  T2h   = (u16*)(ws + 20971520);
    u16*  T3h   = (u16*)(ws + 23068672);
    float* QF   = ws + 25165824;           // [16][128][512] f32 = 1,048,576
    float* KVF  = ws + 26214400;           // [16][128][1024] f32 = 2,097,152
    u16*  OMTh  = (u16*)(ws + 28311552);   // [16][512][128] u16 = 524,288 f
    float* QTr  = ws + 28835840;           // 524,288
    float* QTi  = ws + 29360128;           // 524,288
    u16*  crossh = (u16*)(ws + 29884416);  // [16384][512] u16 = 4,194,304 f
    u16*  Xh    = (u16*)(ws + 34078720);   // 2,097,152 f
    u16*  XTh   = (u16*)(ws + 36175872);   // 2,097,152 f
    u16*  GHh   = (u16*)(ws + 38273024);   // 1,048,576 f
    float* GLG  = ws + 39321600;           // 24,576
    u16*  wqh   = (u16*)(ws + 39346176);   // u16 chain below
    u16*  wkvh  = wqh + 262144;            // 524,288 u16 ([wk; wv])
    u16*  woh   = wkvh + 524288;
    u16*  ff1h  = woh + 262144;            // 1,048,576 u16
    u16*  ff2h  = ff1h + 1048576;
    u16*  d1w1h = ff2h + 1048576;          // 131,072 u16 each
    u16*  d2w1h = d1w1h + 131072;
    u16*  d3w1h = d2w1h + 131072;
    u16*  PKh   = d3w1h + 131072;          // 2,359,296 u16 -> ends 42,295,296 f
    u16*  TW512h  = (u16*)(ws + 42295296); // 65,536 u16
    u16*  TW1024h = (u16*)(ws + 42328064); // 131,072 u16
    u16*  TIh     = (u16*)(ws + 42393600); // 65,536 u16
    float* bkv    = ws + 42426368;         // 1,024
    // overlays:
    float* FEBP = (float*)KVt;             // phase A partials (4,194,304 f)
    u16*  xTh   = (u16*)(ws + 12582912);   // phase A xT ([16][512][512] u16)
    u16*  HIDh  = KVt;                     // phase E hidden (16,777,216 u16)
    u16*  Qh    = Q0t;                     // phase C post-attn overlay
    u16*  Cch   = (u16*)ws;                // phase G conv partials (37,748,736 u16)

    float* outx = (float*)d_out;
    float* outt = outx + 4194304;

    auto g128 = [&](const u16* A, const u16* W, const float* bias, const float* resid,
                    float* C, u16* Cb, int R, int N, int K, int flags,
                    int Z, u64 zsA, u64 zsW, u64 zsC, u64 zsR, int lrsh) {
        dim3 g(N / 128, R / 128, Z);
        hipLaunchKernelGGL(gemm_fp16, g, dim3(256), 0, stream,
                           A, W, bias, resid, C, Cb, R, N, K, flags, zsA, zsW, zsC, zsR, lrsh);
    };
    auto g64 = [&](const u16* A, const u16* W, const float* bias, const float* resid,
                   float* C, u16* Cb, int R, int N, int K, int flags,
                   int Z, u64 zsA, u64 zsW, u64 zsC, u64 zsR) {
        dim3 g(N / 64, R / 64, Z);
        hipLaunchKernelGGL(gemm64, g, dim3(256), 0, stream,
                           A, W, bias, resid, C, Cb, R, N, K, flags, zsA, zsW, zsC, zsR);
    };

    // ---- Prep (single fused kernel) + conv-weight repack ----
    hipLaunchKernelGGL(prep, dim3(2048), dim3(256), 0, stream,
                       wq, wk, wv, wo, w_ff1, w_ff2, d1_w1, d2_w1, d3_w1, cross, bk, bv,
                       wqh, wkvh, woh, ff1h, ff2h, d1w1h, d2w1h, d3w1h, crossh, bkv,
                       TW512h, TW1024h, TIh);
    hipLaunchKernelGGL(repack_p, dim3(9216), dim3(256), 0, stream, p1, p2, p3, PKh);

    // ---- Phase A: x = x + fourier_block(x) ----
    hipLaunchKernelGGL(tr_cast_x, dim3(64, 16), dim3(256), 0, stream, x_in, xTh);
    g64(TW512h, xTh, nullptr, nullptr, QF, nullptr, 128, 512, 512, 16,
        16, 0, (u64)512 * 512, (u64)128 * 512, 0);
    hipLaunchKernelGGL(spec_tr, dim3(8, 16), dim3(256), 0, stream, QF, QTr, QTi);
    hipLaunchKernelGGL(feb_part, dim3(128, 4), dim3(256), 0, stream, QTr, QTi, feb_wr, feb_wi, FEBP);
    hipLaunchKernelGGL(feb_reduce, dim3(2048), dim3(256), 0, stream, FEBP, OMTh);
    g64(TIh, OMTh, nullptr, x_in, X, Xh, 512, 512, 128, 16 | 8,
        16, 0, (u64)512 * 128, (u64)512 * 512, (u64)512 * 512);

    // ---- Phase B: decomp1 ----
    g64(Xh, d1w1h, d1_b1, nullptr, nullptr, GHh, 8192, 256, 512, 1 | 8, 1, 0, 0, 0, 0);
    hipLaunchKernelGGL(gate2, dim3(32), dim3(256), 0, stream, GHh, d1_w2, d1_b2, GLG);
    hipLaunchKernelGGL(decomp_apply, dim3(16384), dim3(256), 0, stream, X, GLG, XT, XTh, T1h);

    // ---- Phase C: x = x + fourier_cross(x, cross) ----
    g128(XTh, wqh, bq, nullptr, nullptr, Q0t, 8192, 512, 512, 32, 1, 0, 0, 0, 0, 9);
    g128(crossh, wkvh, bkv, nullptr, nullptr, KVt, 16384, 1024, 512, 32, 1, 0, 0, 0, 0, 10);
    g64(TW512h, Q0t, nullptr, nullptr, QF, nullptr, 128, 512, 512, 16,
        16, 0, (u64)512 * 512, (u64)128 * 512, 0);
    g64(TW1024h, KVt, nullptr, nullptr, KVF, nullptr, 128, 1024, 1024, 16,
        16, 0, (u64)1024 * 1024, (u64)128 * 1024, 0);
    hipLaunchKernelGGL(spectral_attn, dim3(128), dim3(256), 0, stream, QF, KVF, OMTh);
    g64(TIh, OMTh, nullptr, nullptr, nullptr, Qh, 512, 512, 128, 8,
        16, 0, (u64)512 * 128, (u64)512 * 512, 0);
    g128(Qh, woh, bo, XT, X, Xh, 8192, 512, 512, 16 | 8, 1, 0, 0, 0, 0, 0);

    // ---- Phase D: decomp2 ----
    g64(Xh, d2w1h, d2_b1, nullptr, nullptr, GHh, 8192, 256, 512, 1 | 8, 1, 0, 0, 0, 0);
    hipLaunchKernelGGL(gate2, dim3(32), dim3(256), 0, stream, GHh, d2_w2, d2_b2, GLG);
    hipLaunchKernelGGL(decomp_apply, dim3(16384), dim3(256), 0, stream, X, GLG, XT, XTh, T2h);

    // ---- Phase E: FFN ----
    g128(XTh, ff1h, nullptr, nullptr, nullptr, HIDh, 8192, 2048, 512, 1 | 8, 1, 0, 0, 0, 0, 0);
    g128(HIDh, ff2h, nullptr, XT, X, Xh, 8192, 512, 2048, 16 | 8, 1, 0, 0, 0, 0, 0);

    // ---- Phase F: decomp3 -> d_out x ----
    g64(Xh, d3w1h, d3_b1, nullptr, nullptr, GHh, 8192, 256, 512, 1 | 8, 1, 0, 0, 0, 0);
    hipLaunchKernelGGL(gate2, dim3(32), dim3(256), 0, stream, GHh, d3_w2, d3_b2, GLG);
    hipLaunchKernelGGL(decomp_apply, dim3(16384), dim3(256), 0, stream, X, GLG, outx,
                       (u16*)nullptr, T3h);

    // ---- Phase G: conv partials (z=3 over t, N=1536 over j,oc) + shifted sum ----
    g128(T1h, PKh, nullptr, nullptr, nullptr, Cch, 8192, 1536, 512, 8,
         3, (u64)8192 * 512, (u64)1536 * 512, (u64)8192 * 1536, 0, 0);
    hipLaunchKernelGGL(conv_sum, dim3(2048), dim3(256), 0, stream, Cch, outt);

    (void)in_sizes; (void)n_in; (void)out_size; (void)ws_size;
}